// Round 1
// baseline (993.191 us; speedup 1.0000x reference)
//
#include <hip/hip_runtime.h>
#include <hip/hip_bf16.h>

typedef __attribute__((ext_vector_type(4))) float  f32x4;
typedef __attribute__((ext_vector_type(8))) short  s16x8;
typedef __attribute__((ext_vector_type(4))) short  s16x4;
typedef __attribute__((ext_vector_type(4))) float  fvec4;

__device__ __forceinline__ short f2bf(float f) {
    union { float f; unsigned u; } x; x.f = f;
    unsigned r = x.u + 0x7fffu + ((x.u >> 16) & 1u);
    return (short)(r >> 16);
}

// ---------------- GEMM: C[M,N] = A[M,K] @ B[K,N] + bias ----------------
// A: fp32 or bf16 (row-major). B: fp32 row-major. C: bf16 or fp32.
// 128x128 tile, BK=32, 256 threads (4 waves, 2x2), 16x16x32 bf16 MFMA.
template<bool A_BF16, bool C_BF16>
__global__ __launch_bounds__(256, 2) void gemm_bias(const void* __restrict__ Av,
                                                    const float* __restrict__ B,
                                                    const float* __restrict__ bias,
                                                    void* __restrict__ Cv,
                                                    int M, int N, int K) {
    __shared__ __align__(16) short As[128][40];   // [m][k] bf16, pad 8
    __shared__ __align__(16) short Bs[128][40];   // [n][k] bf16 (transposed), pad 8
    const int tid = threadIdx.x;
    const int lane = tid & 63, wid = tid >> 6;
    const int wr = wid >> 1, wc = wid & 1;
    const int lr = lane & 15, g = lane >> 4;
    const int m0 = blockIdx.y * 128, n0 = blockIdx.x * 128;

    f32x4 acc[4][4] = {};

    for (int k0 = 0; k0 < K; k0 += 32) {
        // ---- stage A tile (128 x 32) as bf16 ----
        if constexpr (A_BF16) {
            const short* A = (const short*)Av;
            #pragma unroll
            for (int i = 0; i < 2; ++i) {
                int f = i * 256 + tid;
                int row = f >> 2, kq = (f & 3) << 3;
                s16x8 v = *(const s16x8*)&A[(size_t)(m0 + row) * K + k0 + kq];
                *(s16x8*)&As[row][kq] = v;
            }
        } else {
            const float* A = (const float*)Av;
            #pragma unroll
            for (int i = 0; i < 4; ++i) {
                int f = i * 256 + tid;
                int row = f >> 3, kq = (f & 7) << 2;
                fvec4 v = *(const fvec4*)&A[(size_t)(m0 + row) * K + k0 + kq];
                s16x4 o;
                o[0] = f2bf(v[0]); o[1] = f2bf(v[1]); o[2] = f2bf(v[2]); o[3] = f2bf(v[3]);
                *(s16x4*)&As[row][kq] = o;
            }
        }
        // ---- stage B tile transposed (32 x 128 -> [n][k]) ----
        {
            int n = tid & 127;
            int kh = (tid >> 7) << 4;   // 0 or 16
            short tmp[16];
            #pragma unroll
            for (int j = 0; j < 16; ++j)
                tmp[j] = f2bf(B[(size_t)(k0 + kh + j) * N + n0 + n]);
            s16x8 w0, w1;
            #pragma unroll
            for (int j = 0; j < 8; ++j) { w0[j] = tmp[j]; w1[j] = tmp[8 + j]; }
            *(s16x8*)&Bs[n][kh] = w0;
            *(s16x8*)&Bs[n][kh + 8] = w1;
        }
        __syncthreads();
        // ---- MFMA ----
        s16x8 af[4], bfr[4];
        #pragma unroll
        for (int m = 0; m < 4; ++m)
            af[m] = *(const s16x8*)&As[wr * 64 + m * 16 + lr][g * 8];
        #pragma unroll
        for (int n = 0; n < 4; ++n)
            bfr[n] = *(const s16x8*)&Bs[wc * 64 + n * 16 + lr][g * 8];
        #pragma unroll
        for (int m = 0; m < 4; ++m)
            #pragma unroll
            for (int n = 0; n < 4; ++n)
                acc[m][n] = __builtin_amdgcn_mfma_f32_16x16x32_bf16(af[m], bfr[n], acc[m][n], 0, 0, 0);
        __syncthreads();
    }
    // ---- epilogue: C = acc + bias ----
    #pragma unroll
    for (int m = 0; m < 4; ++m) {
        #pragma unroll
        for (int j = 0; j < 4; ++j) {
            int row = m0 + wr * 64 + m * 16 + g * 4 + j;
            #pragma unroll
            for (int n = 0; n < 4; ++n) {
                int col = n0 + wc * 64 + n * 16 + lr;
                float v = acc[m][n][j] + bias[col];
                if constexpr (C_BF16) ((short*)Cv)[(size_t)row * N + col] = f2bf(v);
                else                  ((float*)Cv)[(size_t)row * N + col] = v;
            }
        }
    }
}

// ---------------- Flash attention (causal, GQA) ----------------
// Q: [B*S, 2048] bf16, K/V: [B*S, 512] bf16, Oa: [B*S, 2048] bf16
// grid: B*NH*(S/64) blocks, 256 threads (4 waves), wave owns 16 q-rows.
__global__ __launch_bounds__(256, 2) void attn_kernel(const short* __restrict__ Q,
                                                      const short* __restrict__ Kb,
                                                      const short* __restrict__ Vb,
                                                      short* __restrict__ Oa) {
    __shared__ __align__(16) short Ks[32][136];     // [kv][d], pad 8
    __shared__ __align__(16) short Vs[128][40];     // [d][kv] transposed, pad 8
    __shared__ __align__(16) short Ps[4][16][40];   // per-wave P tile [q][kv], pad 8
    const int tid = threadIdx.x, lane = tid & 63, wid = tid >> 6;
    const int lr = lane & 15, g = lane >> 4;
    const int bid = blockIdx.x;
    const int qt = bid & 31, h = (bid >> 5) & 15, b = bid >> 9;
    const int kvh = h >> 2;
    const int q0 = qt * 64;
    const float scale = 0.08838834764831845f;  // 1/sqrt(128)

    // Q fragments: wave's 16 rows x 128 d, A-operand layout
    s16x8 qf[4];
    {
        size_t qrow = (size_t)b * 2048 + q0 + wid * 16 + lr;
        #pragma unroll
        for (int c = 0; c < 4; ++c)
            qf[c] = *(const s16x8*)&Q[qrow * 2048 + h * 128 + c * 32 + g * 8];
    }
    float m_run[4], l_run[4];
    #pragma unroll
    for (int j = 0; j < 4; ++j) { m_run[j] = -1e30f; l_run[j] = 0.f; }
    f32x4 oacc[8] = {};

    const int tmask = q0 >> 5;
    const int ntiles = tmask + 2;
    for (int t = 0; t < ntiles; ++t) {
        const int kv0 = t << 5;
        // ---- stage K tile (32 kv x 128 d) ----
        #pragma unroll
        for (int i = 0; i < 2; ++i) {
            int f = i * 256 + tid;
            int r = f >> 4, dq = (f & 15) << 3;
            *(s16x8*)&Ks[r][dq] =
                *(const s16x8*)&Kb[((size_t)b * 2048 + kv0 + r) * 512 + kvh * 128 + dq];
        }
        // ---- stage V tile transposed ([d][kv]) ----
        {
            int d = tid & 127;
            int kh = (tid >> 7) << 4;   // 0 or 16
            short tmp[16];
            #pragma unroll
            for (int j = 0; j < 16; ++j)
                tmp[j] = Vb[((size_t)b * 2048 + kv0 + kh + j) * 512 + kvh * 128 + d];
            s16x8 w0, w1;
            #pragma unroll
            for (int j = 0; j < 8; ++j) { w0[j] = tmp[j]; w1[j] = tmp[8 + j]; }
            *(s16x8*)&Vs[d][kh] = w0;
            *(s16x8*)&Vs[d][kh + 8] = w1;
        }
        __syncthreads();
        // ---- S = Q K^T (16 x 32) ----
        f32x4 s0 = {}, s1 = {};
        #pragma unroll
        for (int c = 0; c < 4; ++c) {
            s16x8 kf0 = *(const s16x8*)&Ks[lr][c * 32 + g * 8];
            s16x8 kf1 = *(const s16x8*)&Ks[16 + lr][c * 32 + g * 8];
            s0 = __builtin_amdgcn_mfma_f32_16x16x32_bf16(qf[c], kf0, s0, 0, 0, 0);
            s1 = __builtin_amdgcn_mfma_f32_16x16x32_bf16(qf[c], kf1, s1, 0, 0, 0);
        }
        // ---- online softmax ----
        const bool domask = (t >= tmask);
        #pragma unroll
        for (int j = 0; j < 4; ++j) {
            int rq = q0 + wid * 16 + g * 4 + j;
            float v0 = s0[j] * scale;
            float v1 = s1[j] * scale;
            if (domask) {
                if (kv0 + lr > rq)      v0 = -1e30f;
                if (kv0 + 16 + lr > rq) v1 = -1e30f;
            }
            float mx = fmaxf(v0, v1);
            #pragma unroll
            for (int d = 1; d < 16; d <<= 1)
                mx = fmaxf(mx, __shfl_xor(mx, d));
            float mn = fmaxf(m_run[j], mx);
            float fs = __expf(m_run[j] - mn);
            float p0 = __expf(v0 - mn);
            float p1 = __expf(v1 - mn);
            float ps = p0 + p1;
            #pragma unroll
            for (int d = 1; d < 16; d <<= 1)
                ps += __shfl_xor(ps, d);
            l_run[j] = l_run[j] * fs + ps;
            m_run[j] = mn;
            #pragma unroll
            for (int n = 0; n < 8; ++n) oacc[n][j] *= fs;
            Ps[wid][g * 4 + j][lr] = f2bf(p0);
            Ps[wid][g * 4 + j][16 + lr] = f2bf(p1);
        }
        asm volatile("s_waitcnt lgkmcnt(0)" ::: "memory");
        __builtin_amdgcn_sched_barrier(0);
        // ---- O += P V ----
        s16x8 pf = *(const s16x8*)&Ps[wid][lr][g * 8];
        #pragma unroll
        for (int n = 0; n < 8; ++n) {
            s16x8 vf = *(const s16x8*)&Vs[n * 16 + lr][g * 8];
            oacc[n] = __builtin_amdgcn_mfma_f32_16x16x32_bf16(pf, vf, oacc[n], 0, 0, 0);
        }
        __syncthreads();
    }
    // ---- normalize + store ----
    #pragma unroll
    for (int j = 0; j < 4; ++j) {
        float inv = 1.0f / l_run[j];
        size_t row = (size_t)b * 2048 + q0 + wid * 16 + g * 4 + j;
        #pragma unroll
        for (int n = 0; n < 8; ++n)
            Oa[row * 2048 + h * 128 + n * 16 + lr] = f2bf(oacc[n][j] * inv);
    }
}

extern "C" void kernel_launch(void* const* d_in, const int* in_sizes, int n_in,
                              void* d_out, int out_size, void* d_ws, size_t ws_size,
                              hipStream_t stream) {
    const float* x  = (const float*)d_in[0];
    const float* Wq = (const float*)d_in[1];
    const float* bq = (const float*)d_in[2];
    const float* Wk = (const float*)d_in[3];
    const float* bk = (const float*)d_in[4];
    const float* Wv = (const float*)d_in[5];
    const float* bv = (const float*)d_in[6];
    const float* Wo = (const float*)d_in[7];
    const float* bo = (const float*)d_in[8];
    float* out = (float*)d_out;

    char* ws = (char*)d_ws;
    short* Qb = (short*)(ws);                          // 8192*2048 bf16 = 32 MiB
    short* Kb = (short*)(ws + (size_t)33554432);       // 8192*512  bf16 =  8 MiB
    short* Vb = (short*)(ws + (size_t)41943040);       // 8192*512  bf16 =  8 MiB
    short* Ab = (short*)(ws + (size_t)50331648);       // 8192*2048 bf16 = 32 MiB

    const int M = 8192, D = 2048, NKVD = 512;
    gemm_bias<false, true><<<dim3(D / 128,    M / 128), 256, 0, stream>>>(x, Wq, bq, Qb, M, D, D);
    gemm_bias<false, true><<<dim3(NKVD / 128, M / 128), 256, 0, stream>>>(x, Wk, bk, Kb, M, NKVD, D);
    gemm_bias<false, true><<<dim3(NKVD / 128, M / 128), 256, 0, stream>>>(x, Wv, bv, Vb, M, NKVD, D);
    attn_kernel<<<dim3(4 * 16 * (2048 / 64)), 256, 0, stream>>>(Qb, Kb, Vb, Ab);
    gemm_bias<true, false><<<dim3(D / 128,    M / 128), 256, 0, stream>>>(Ab, Wo, bo, out, M, D, D);
}

// Round 2
// 670.814 us; speedup vs baseline: 1.4806x; 1.4806x over previous
//
#include <hip/hip_runtime.h>
#include <hip/hip_bf16.h>

typedef __attribute__((ext_vector_type(4))) float  f32x4;
typedef __attribute__((ext_vector_type(8))) short  s16x8;
typedef __attribute__((ext_vector_type(4))) short  s16x4;
typedef __attribute__((ext_vector_type(4))) float  fvec4;

__device__ __forceinline__ short f2bf(float f) {
    union { float f; unsigned u; } x; x.f = f;
    unsigned r = x.u + 0x7fffu + ((x.u >> 16) & 1u);
    return (short)(r >> 16);
}

__device__ __forceinline__ void gload_lds16(const short* g, short* lds) {
    __builtin_amdgcn_global_load_lds(
        (const __attribute__((address_space(1))) void*)g,
        (__attribute__((address_space(3))) void*)lds, 16, 0, 0);
}

// ---------------- fp32 -> bf16 elementwise convert ----------------
__global__ __launch_bounds__(256) void convert_bf16(const float* __restrict__ X,
                                                    short* __restrict__ Y) {
    size_t i = ((size_t)blockIdx.x * 256 + threadIdx.x) * 8;
    fvec4 a = *(const fvec4*)&X[i];
    fvec4 b = *(const fvec4*)&X[i + 4];
    s16x8 o;
    o[0] = f2bf(a[0]); o[1] = f2bf(a[1]); o[2] = f2bf(a[2]); o[3] = f2bf(a[3]);
    o[4] = f2bf(b[0]); o[5] = f2bf(b[1]); o[6] = f2bf(b[2]); o[7] = f2bf(b[3]);
    *(s16x8*)&Y[i] = o;
}

// ---------------- fp32 [K][N] -> bf16 [N][K] transpose+convert ----------------
__global__ __launch_bounds__(256) void tconv(const float* __restrict__ W,
                                             short* __restrict__ Wt,
                                             int K, int N) {
    __shared__ float tile[32][33];
    const int k0 = blockIdx.x * 32, n0 = blockIdx.y * 32;
    const int tx = threadIdx.x & 31, ty = threadIdx.x >> 5;
    #pragma unroll
    for (int i = 0; i < 4; ++i) {
        int k = ty + i * 8;
        tile[k][tx] = W[(size_t)(k0 + k) * N + n0 + tx];
    }
    __syncthreads();
    #pragma unroll
    for (int i = 0; i < 4; ++i) {
        int n = ty + i * 8;
        Wt[(size_t)(n0 + n) * K + k0 + tx] = f2bf(tile[tx][n]);
    }
}

// ---------------- GEMM: C[M,N] = A[M,K] @ Bt[N,K]^T + bias ----------------
// m97 structure: 128x128 tile, BK=64, 4 waves (2x2), global_load_lds width 16.
template<bool C_BF16>
__global__ __launch_bounds__(256) void gemm_bt(const short* __restrict__ A,
                                               const short* __restrict__ Bt,
                                               const float* __restrict__ bias,
                                               void* __restrict__ Cv,
                                               int M, int N, int K) {
    __shared__ __align__(16) short As[128 * 64];
    __shared__ __align__(16) short Bs[128 * 64];
    const int tid = threadIdx.x, lane = tid & 63, wid = tid >> 6;
    const int wr = wid >> 1, wc = wid & 1;
    const int lr = lane & 15, g = lane >> 4;
    const int m0 = blockIdx.y * 128, n0 = blockIdx.x * 128;
    const int r8 = lane >> 3, c8 = lane & 7;

    f32x4 acc[4][4] = {};

    const short* ga = A  + (size_t)(m0 + wid * 8 + r8) * K + c8 * 8;
    const short* gb = Bt + (size_t)(n0 + wid * 8 + r8) * K + c8 * 8;

    for (int k0 = 0; k0 < K; k0 += 64) {
        #pragma unroll
        for (int it = 0; it < 4; ++it) {
            gload_lds16(ga + (size_t)(it * 32) * K + k0, &As[(wid * 8 + it * 32) * 64]);
            gload_lds16(gb + (size_t)(it * 32) * K + k0, &Bs[(wid * 8 + it * 32) * 64]);
        }
        __syncthreads();
        #pragma unroll
        for (int kk = 0; kk < 2; ++kk) {
            s16x8 af[4], bfv[4];
            #pragma unroll
            for (int m = 0; m < 4; ++m)
                af[m] = *(const s16x8*)&As[(wr * 64 + m * 16 + lr) * 64 + kk * 32 + g * 8];
            #pragma unroll
            for (int n = 0; n < 4; ++n)
                bfv[n] = *(const s16x8*)&Bs[(wc * 64 + n * 16 + lr) * 64 + kk * 32 + g * 8];
            #pragma unroll
            for (int m = 0; m < 4; ++m)
                #pragma unroll
                for (int n = 0; n < 4; ++n)
                    acc[m][n] = __builtin_amdgcn_mfma_f32_16x16x32_bf16(af[m], bfv[n], acc[m][n], 0, 0, 0);
        }
        __syncthreads();
    }
    #pragma unroll
    for (int m = 0; m < 4; ++m) {
        #pragma unroll
        for (int j = 0; j < 4; ++j) {
            int row = m0 + wr * 64 + m * 16 + g * 4 + j;
            #pragma unroll
            for (int n = 0; n < 4; ++n) {
                int col = n0 + wc * 64 + n * 16 + lr;
                float v = acc[m][n][j] + bias[col];
                if constexpr (C_BF16) ((short*)Cv)[(size_t)row * N + col] = f2bf(v);
                else                  ((float*)Cv)[(size_t)row * N + col] = v;
            }
        }
    }
}

// ---------------- Flash attention (causal, GQA) ----------------
// Q: [B*S, 2048] bf16, K/V: [B*S, kvstride] bf16, Oa: [B*S, 2048] bf16
__global__ __launch_bounds__(256, 2) void attn_kernel(const short* __restrict__ Q,
                                                      const short* __restrict__ Kb,
                                                      const short* __restrict__ Vb,
                                                      int kvstride,
                                                      short* __restrict__ Oa) {
    __shared__ __align__(16) short Ks[32][136];     // [kv][d], pad 8
    __shared__ __align__(16) short Vs[128][40];     // [d][kv] transposed, pad 8
    __shared__ __align__(16) short Ps[4][16][40];   // per-wave P tile [q][kv], pad 8
    const int tid = threadIdx.x, lane = tid & 63, wid = tid >> 6;
    const int lr = lane & 15, g = lane >> 4;
    const int bid = blockIdx.x;
    const int qt = bid & 31, h = (bid >> 5) & 15, b = bid >> 9;
    const int kvh = h >> 2;
    const int q0 = qt * 64;
    const float scale = 0.08838834764831845f;  // 1/sqrt(128)

    s16x8 qf[4];
    {
        size_t qrow = (size_t)b * 2048 + q0 + wid * 16 + lr;
        #pragma unroll
        for (int c = 0; c < 4; ++c)
            qf[c] = *(const s16x8*)&Q[qrow * 2048 + h * 128 + c * 32 + g * 8];
    }
    float m_run[4], l_run[4];
    #pragma unroll
    for (int j = 0; j < 4; ++j) { m_run[j] = -1e30f; l_run[j] = 0.f; }
    f32x4 oacc[8] = {};

    const int tmask = q0 >> 5;
    const int ntiles = tmask + 2;
    for (int t = 0; t < ntiles; ++t) {
        const int kv0 = t << 5;
        #pragma unroll
        for (int i = 0; i < 2; ++i) {
            int f = i * 256 + tid;
            int r = f >> 4, dq = (f & 15) << 3;
            *(s16x8*)&Ks[r][dq] =
                *(const s16x8*)&Kb[((size_t)b * 2048 + kv0 + r) * kvstride + kvh * 128 + dq];
        }
        {
            int d = tid & 127;
            int kh = (tid >> 7) << 4;
            short tmp[16];
            #pragma unroll
            for (int j = 0; j < 16; ++j)
                tmp[j] = Vb[((size_t)b * 2048 + kv0 + kh + j) * kvstride + kvh * 128 + d];
            s16x8 w0, w1;
            #pragma unroll
            for (int j = 0; j < 8; ++j) { w0[j] = tmp[j]; w1[j] = tmp[8 + j]; }
            *(s16x8*)&Vs[d][kh] = w0;
            *(s16x8*)&Vs[d][kh + 8] = w1;
        }
        __syncthreads();
        f32x4 s0 = {}, s1 = {};
        #pragma unroll
        for (int c = 0; c < 4; ++c) {
            s16x8 kf0 = *(const s16x8*)&Ks[lr][c * 32 + g * 8];
            s16x8 kf1 = *(const s16x8*)&Ks[16 + lr][c * 32 + g * 8];
            s0 = __builtin_amdgcn_mfma_f32_16x16x32_bf16(qf[c], kf0, s0, 0, 0, 0);
            s1 = __builtin_amdgcn_mfma_f32_16x16x32_bf16(qf[c], kf1, s1, 0, 0, 0);
        }
        const bool domask = (t >= tmask);
        #pragma unroll
        for (int j = 0; j < 4; ++j) {
            int rq = q0 + wid * 16 + g * 4 + j;
            float v0 = s0[j] * scale;
            float v1 = s1[j] * scale;
            if (domask) {
                if (kv0 + lr > rq)      v0 = -1e30f;
                if (kv0 + 16 + lr > rq) v1 = -1e30f;
            }
            float mx = fmaxf(v0, v1);
            #pragma unroll
            for (int d = 1; d < 16; d <<= 1)
                mx = fmaxf(mx, __shfl_xor(mx, d));
            float mn = fmaxf(m_run[j], mx);
            float fs = __expf(m_run[j] - mn);
            float p0 = __expf(v0 - mn);
            float p1 = __expf(v1 - mn);
            float ps = p0 + p1;
            #pragma unroll
            for (int d = 1; d < 16; d <<= 1)
                ps += __shfl_xor(ps, d);
            l_run[j] = l_run[j] * fs + ps;
            m_run[j] = mn;
            #pragma unroll
            for (int n = 0; n < 8; ++n) oacc[n][j] *= fs;
            Ps[wid][g * 4 + j][lr] = f2bf(p0);
            Ps[wid][g * 4 + j][16 + lr] = f2bf(p1);
        }
        asm volatile("s_waitcnt lgkmcnt(0)" ::: "memory");
        __builtin_amdgcn_sched_barrier(0);
        s16x8 pf = *(const s16x8*)&Ps[wid][lr][g * 8];
        #pragma unroll
        for (int n = 0; n < 8; ++n) {
            s16x8 vf = *(const s16x8*)&Vs[n * 16 + lr][g * 8];
            oacc[n] = __builtin_amdgcn_mfma_f32_16x16x32_bf16(pf, vf, oacc[n], 0, 0, 0);
        }
        __syncthreads();
    }
    #pragma unroll
    for (int j = 0; j < 4; ++j) {
        float inv = 1.0f / l_run[j];
        size_t row = (size_t)b * 2048 + q0 + wid * 16 + g * 4 + j;
        #pragma unroll
        for (int n = 0; n < 8; ++n)
            Oa[row * 2048 + h * 128 + n * 16 + lr] = f2bf(oacc[n][j] * inv);
    }
}

extern "C" void kernel_launch(void* const* d_in, const int* in_sizes, int n_in,
                              void* d_out, int out_size, void* d_ws, size_t ws_size,
                              hipStream_t stream) {
    const float* x  = (const float*)d_in[0];
    const float* Wq = (const float*)d_in[1];
    const float* bq = (const float*)d_in[2];
    const float* Wk = (const float*)d_in[3];
    const float* bk = (const float*)d_in[4];
    const float* Wv = (const float*)d_in[5];
    const float* bv = (const float*)d_in[6];
    const float* Wo = (const float*)d_in[7];
    const float* bo = (const float*)d_in[8];
    float* out = (float*)d_out;

    // ws layout (80 MiB total):
    //   Xb  [0, 32MiB)      x in bf16; WoT reuses offset 0 after Xb is dead
    //   Qb  [32, 64MiB)     Q projection; attention output written in-place
    //   KVb [64, 80MiB)     K|V projection, row stride 1024 (cols 0-511 K, 512-1023 V)
    // d_out used as scratch until the final GEMM overwrites all of it:
    //   WqT     dout[0, 8MiB)
    //   WkvT    dout[8, 12MiB)
    //   bias_kv dout[12MiB, +4KiB)
    char* ws = (char*)d_ws;
    short* Xb   = (short*)(ws);
    short* Qb   = (short*)(ws + (size_t)33554432);
    short* KVb  = (short*)(ws + (size_t)67108864);
    short* WoT  = (short*)(ws);  // after Xb dead
    char* dob = (char*)d_out;
    short* WqT  = (short*)(dob);
    short* WkvT = (short*)(dob + (size_t)8388608);
    float* bias_kv = (float*)(dob + (size_t)12582912);

    const int M = 8192, D = 2048;

    // 1. x -> bf16
    convert_bf16<<<dim3((M * D) / (256 * 8)), 256, 0, stream>>>(x, Xb);
    // 2. weight transposes into d_out scratch
    tconv<<<dim3(64, 64), 256, 0, stream>>>(Wq, WqT, D, D);
    tconv<<<dim3(64, 16), 256, 0, stream>>>(Wk, WkvT, D, 512);
    tconv<<<dim3(64, 16), 256, 0, stream>>>(Wv, WkvT + (size_t)512 * D, D, 512);
    // 3. concat biases for fused KV gemm
    hipMemcpyAsync(bias_kv,       bk, 512 * sizeof(float), hipMemcpyDeviceToDevice, stream);
    hipMemcpyAsync(bias_kv + 512, bv, 512 * sizeof(float), hipMemcpyDeviceToDevice, stream);
    // 4. projections
    gemm_bt<true><<<dim3(16, 64), 256, 0, stream>>>(Xb, WqT,  bq,      Qb,  M, 2048, D);
    gemm_bt<true><<<dim3(8,  64), 256, 0, stream>>>(Xb, WkvT, bias_kv, KVb, M, 1024, D);
    // 5. Wo transpose into the (now dead) Xb region
    tconv<<<dim3(64, 64), 256, 0, stream>>>(Wo, WoT, D, D);
    // 6. attention (in-place over Qb)
    attn_kernel<<<dim3(4 * 16 * (2048 / 64)), 256, 0, stream>>>(Qb, KVb, KVb + 512, 1024, Qb);
    // 7. output projection
    gemm_bt<false><<<dim3(16, 64), 256, 0, stream>>>(Qb, WoT, bo, out, M, 2048, D);
}

// Round 5
// 439.518 us; speedup vs baseline: 2.2597x; 1.5263x over previous
//
#include <hip/hip_runtime.h>
#include <hip/hip_bf16.h>

typedef __attribute__((ext_vector_type(4)))  float f32x4;
typedef __attribute__((ext_vector_type(16))) float f32x16;
typedef __attribute__((ext_vector_type(8)))  short s16x8;
typedef __attribute__((ext_vector_type(4)))  short s16x4;
typedef __attribute__((ext_vector_type(4)))  float fvec4;

__device__ __forceinline__ short f2bf(float f) {
    union { float f; unsigned u; } x; x.f = f;
    unsigned r = x.u + 0x7fffu + ((x.u >> 16) & 1u);
    return (short)(r >> 16);
}

__device__ __forceinline__ void gload_lds16(const short* g, short* lds) {
    __builtin_amdgcn_global_load_lds(
        (const __attribute__((address_space(1))) void*)g,
        (__attribute__((address_space(3))) void*)lds, 16, 0, 0);
}

// ---------------- fp32 -> bf16 elementwise convert ----------------
__global__ __launch_bounds__(256) void convert_bf16(const float* __restrict__ X,
                                                    short* __restrict__ Y) {
    size_t i = ((size_t)blockIdx.x * 256 + threadIdx.x) * 8;
    fvec4 a = *(const fvec4*)&X[i];
    fvec4 b = *(const fvec4*)&X[i + 4];
    s16x8 o;
    o[0] = f2bf(a[0]); o[1] = f2bf(a[1]); o[2] = f2bf(a[2]); o[3] = f2bf(a[3]);
    o[4] = f2bf(b[0]); o[5] = f2bf(b[1]); o[6] = f2bf(b[2]); o[7] = f2bf(b[3]);
    *(s16x8*)&Y[i] = o;
}

// ---------------- fp32 [K][N] -> bf16 [N][K] transpose+convert ----------------
__global__ __launch_bounds__(256) void tconv(const float* __restrict__ W,
                                             short* __restrict__ Wt,
                                             int K, int N) {
    __shared__ float tile[32][33];
    const int k0 = blockIdx.x * 32, n0 = blockIdx.y * 32;
    const int tx = threadIdx.x & 31, ty = threadIdx.x >> 5;
    #pragma unroll
    for (int i = 0; i < 4; ++i) {
        int k = ty + i * 8;
        tile[k][tx] = W[(size_t)(k0 + k) * N + n0 + tx];
    }
    __syncthreads();
    #pragma unroll
    for (int i = 0; i < 4; ++i) {
        int n = ty + i * 8;
        Wt[(size_t)(n0 + n) * K + k0 + tx] = f2bf(tile[tx][n]);
    }
}

// ---------------- GEMM: C[M,N] = A[M,K] @ Bt[N,K]^T + bias ----------------
// MODE 0: f32 C row-major; 1: bf16 C row-major; 2: bf16 V-transposed epilogue
template<int MODE>
__global__ __launch_bounds__(256) void gemm_bt(const short* __restrict__ A,
                                               const short* __restrict__ Bt,
                                               const float* __restrict__ bias,
                                               void* __restrict__ Cv,
                                               int M, int N, int K) {
    __shared__ __align__(16) short As[128 * 64];
    __shared__ __align__(16) short Bs[128 * 64];
    const int tid = threadIdx.x, lane = tid & 63, wid = tid >> 6;
    const int wr = wid >> 1, wc = wid & 1;
    const int lr = lane & 15, g = lane >> 4;
    const int m0 = blockIdx.y * 128, n0 = blockIdx.x * 128;
    const int r8 = lane >> 3, c8 = lane & 7;

    f32x4 acc[4][4] = {};

    const short* ga = A  + (size_t)(m0 + wid * 8 + r8) * K + c8 * 8;
    const short* gb = Bt + (size_t)(n0 + wid * 8 + r8) * K + c8 * 8;

    for (int k0 = 0; k0 < K; k0 += 64) {
        #pragma unroll
        for (int it = 0; it < 4; ++it) {
            gload_lds16(ga + (size_t)(it * 32) * K + k0, &As[(wid * 8 + it * 32) * 64]);
            gload_lds16(gb + (size_t)(it * 32) * K + k0, &Bs[(wid * 8 + it * 32) * 64]);
        }
        __syncthreads();
        #pragma unroll
        for (int kk = 0; kk < 2; ++kk) {
            s16x8 af[4], bfv[4];
            #pragma unroll
            for (int m = 0; m < 4; ++m)
                af[m] = *(const s16x8*)&As[(wr * 64 + m * 16 + lr) * 64 + kk * 32 + g * 8];
            #pragma unroll
            for (int n = 0; n < 4; ++n)
                bfv[n] = *(const s16x8*)&Bs[(wc * 64 + n * 16 + lr) * 64 + kk * 32 + g * 8];
            #pragma unroll
            for (int m = 0; m < 4; ++m)
                #pragma unroll
                for (int n = 0; n < 4; ++n)
                    acc[m][n] = __builtin_amdgcn_mfma_f32_16x16x32_bf16(af[m], bfv[n], acc[m][n], 0, 0, 0);
        }
        __syncthreads();
    }
    #pragma unroll
    for (int m = 0; m < 4; ++m) {
        if constexpr (MODE == 2) {
            // V projection: store transposed Vt[(b*4+kvh)*128 + d][s], s16x4 over 4 rows
            #pragma unroll
            for (int n = 0; n < 4; ++n) {
                int col = n0 + wc * 64 + n * 16 + lr;       // 0..511
                int kvh = col >> 7, d = col & 127;
                int row0 = m0 + wr * 64 + m * 16 + g * 4;
                int b = row0 >> 11, s0 = row0 & 2047;
                s16x4 o;
                #pragma unroll
                for (int j = 0; j < 4; ++j) o[j] = f2bf(acc[m][n][j] + bias[col]);
                *(s16x4*)&((short*)Cv)[(((size_t)b * 4 + kvh) * 128 + d) * 2048 + s0] = o;
            }
        } else {
            #pragma unroll
            for (int j = 0; j < 4; ++j) {
                int row = m0 + wr * 64 + m * 16 + g * 4 + j;
                #pragma unroll
                for (int n = 0; n < 4; ++n) {
                    int col = n0 + wc * 64 + n * 16 + lr;
                    float v = acc[m][n][j] + bias[col];
                    if constexpr (MODE == 1) ((short*)Cv)[(size_t)row * N + col] = f2bf(v);
                    else                     ((float*)Cv)[(size_t)row * N + col] = v;
                }
            }
        }
    }
}

// ---------------- Flash attention: 8 waves x 32 q-rows, KVBLK=64, 32x32x16 ----
// Q: [8192][2048] bf16. Kg: [8192][512] bf16. Vtg: [16][128][2048] bf16 (b*4+kvh, d, s)
// Oa = Q buffer (in-place, head column slice).
__global__ __launch_bounds__(512, 1) void attn_kernel(const short* __restrict__ Q,
                                                      const short* __restrict__ Kg,
                                                      const short* __restrict__ Vtg,
                                                      short* __restrict__ Oa) {
    __shared__ __align__(16) short Klds[2][8192];   // [64 kv][128 d], 16B-slot XOR-swizzled
    __shared__ __align__(16) short Vlds[2][8192];   // [128 d][64 kv], swizzled
    __shared__ __align__(16) short Plds[8][32][72]; // per-wave P [q][kv], pad 8
    const int tid = threadIdx.x;
    const int lane = tid & 63, w = tid >> 6;
    const int l31 = lane & 31, hi = lane >> 5, e7 = lane & 7;
    const int ve = hi ^ e7;

    const int bid = blockIdx.x;
    const int phase = bid >> 8, idx = bid & 255;
    const int bh = idx >> 2;
    const int b = bh >> 4, h = bh & 15;
    const int qt = phase ? (3 - (idx & 3)) : (4 + (idx & 3));
    const int qb = qt << 8;
    const int kvh = h >> 2;
    const float scale = 0.08838834764831845f;   // 1/sqrt(128)

    const int q_min = qb + w * 32;
    const int qg = q_min + l31;
    const size_t qrow = (size_t)b * 2048 + qg;

    // Q fragments: B-operand, lane holds Q[qg][c*16 + hi*8 + 0..7]
    s16x8 qf[8];
    #pragma unroll
    for (int c = 0; c < 8; ++c)
        qf[c] = *(const s16x8*)&Q[qrow * 2048 + h * 128 + c * 16 + hi * 8];

    f32x16 oacc[4] = {};
    // m_run init must stay >> mask value (-1e30) so fully-masked scores give
    // exp((-1e30 - m_run)*scale) = 0, not exp(0) = 1.
    float m_run = -1e28f, l_run = 0.f;

    const int nt = (qb >> 6) + 4;
    const int tp_w = q_min >> 6;

    const short* Kbase = Kg + ((size_t)b * 2048) * 512 + kvh * 128;
    const short* Vbase = Vtg + ((size_t)(b * 4 + kvh)) * 128 * 2048;

    const int krow0 = w * 4 + (lane >> 4), kslot = lane & 15;
    const int vrow0 = w * 8 + (lane >> 3), vslot = lane & 7;

#define STAGE(buf, t) do {                                                        \
    const int kv0_ = (t) << 6;                                                    \
    _Pragma("unroll")                                                             \
    for (int s_ = 0; s_ < 2; ++s_) {                                              \
        int kr = s_ * 32 + krow0;                                                 \
        gload_lds16(Kbase + (size_t)(kv0_ + kr) * 512 + (kslot ^ (kr & 7)) * 8,   \
                    &Klds[buf][s_ * 4096 + w * 512]);                             \
        int vr = s_ * 64 + vrow0;                                                 \
        gload_lds16(Vbase + (size_t)vr * 2048 + kv0_ + (vslot ^ (vr & 7)) * 8,    \
                    &Vlds[buf][s_ * 4096 + w * 512]);                             \
    }                                                                             \
} while (0)

    STAGE(0, 0);
    __syncthreads();

    int cur = 0;
    for (int t = 0; t < nt; ++t) {
        if (t + 1 < nt) STAGE(cur ^ 1, t + 1);
        if (t <= tp_w) {
            // ---- S^T = K Q^T : two 32-kv subtiles ----
            f32x16 s0 = {}, s1 = {};
            const short* kb = &Klds[cur][l31 * 128];
            #pragma unroll
            for (int c = 0; c < 8; ++c) {
                int sl = (((c << 1) ^ ve)) * 8;
                s16x8 kf0 = *(const s16x8*)&kb[sl];
                s16x8 kf1 = *(const s16x8*)&kb[4096 + sl];
                s0 = __builtin_amdgcn_mfma_f32_32x32x16_bf16(kf0, qf[c], s0, 0, 0, 0);
                s1 = __builtin_amdgcn_mfma_f32_32x32x16_bf16(kf1, qf[c], s1, 0, 0, 0);
            }
            // ---- causal mask (exactly one partial tile per wave) ----
            if (t == tp_w) {
                const int qrel = qg - (t << 6) - 4 * hi;
                #pragma unroll
                for (int r = 0; r < 16; ++r) {
                    const int rw = (r & 3) + 8 * (r >> 2);
                    if (rw > qrel)      s0[r] = -1e30f;
                    if (rw + 32 > qrel) s1[r] = -1e30f;
                }
            }
            // ---- softmax (in-register, swapped layout: q = lane&31) ----
            float mx[16];
            #pragma unroll
            for (int r = 0; r < 16; ++r) mx[r] = fmaxf(s0[r], s1[r]);
            #pragma unroll
            for (int d = 8; d >= 1; d >>= 1)
                #pragma unroll
                for (int r = 0; r < d; ++r) mx[r] = fmaxf(mx[r], mx[r + d]);
            float pmax = mx[0];
            pmax = fmaxf(pmax, __shfl_xor(pmax, 32));   // combine lane/partner halves
            if (!__all(pmax <= m_run + 90.5f)) {   // 8/scale: defer-max threshold
                float mn = fmaxf(m_run, pmax);
                float fs = __expf((m_run - mn) * scale);
                l_run *= fs;
                #pragma unroll
                for (int dn = 0; dn < 4; ++dn)
                    #pragma unroll
                    for (int r = 0; r < 16; ++r) oacc[dn][r] *= fs;
                m_run = mn;
            }
            const float mb = m_run * scale;
            float psum = 0.f;
            #pragma unroll
            for (int r = 0; r < 16; ++r) {
                s0[r] = __expf(fmaf(s0[r], scale, -mb));
                s1[r] = __expf(fmaf(s1[r], scale, -mb));
                psum += s0[r] + s1[r];
            }
            l_run += psum + __shfl_xor(psum, 32);       // own + partner halves
            // ---- P -> per-wave LDS roundtrip (verified C/D layout -> B layout) ----
            short* Pw = (short*)&Plds[w][0][0];
            #pragma unroll
            for (int u = 0; u < 4; ++u) {
                s16x4 w0, w1;
                #pragma unroll
                for (int j = 0; j < 4; ++j) { w0[j] = f2bf(s0[4*u+j]); w1[j] = f2bf(s1[4*u+j]); }
                *(s16x4*)&Pw[l31 * 72 + u * 8 + hi * 4]      = w0;   // kv = u*8+hi*4+j
                *(s16x4*)&Pw[l31 * 72 + 32 + u * 8 + hi * 4] = w1;   // kv = 32+...
            }
            asm volatile("s_waitcnt lgkmcnt(0)" ::: "memory");
            __builtin_amdgcn_sched_barrier(0);
            s16x8 pa[4];
            #pragma unroll
            for (int ks = 0; ks < 4; ++ks)
                pa[ks] = *(const s16x8*)&Pw[l31 * 72 + ks * 16 + hi * 8];
            // ---- O^T += Vt P : A = Vt frag, B = P ----
            const short* vb = &Vlds[cur][l31 * 64];
            #pragma unroll
            for (int ks = 0; ks < 4; ++ks) {
                int sl = (((ks << 1) ^ ve)) * 8;
                #pragma unroll
                for (int dn = 0; dn < 4; ++dn) {
                    s16x8 vf = *(const s16x8*)&vb[dn * 2048 + sl];
                    oacc[dn] = __builtin_amdgcn_mfma_f32_32x32x16_bf16(vf, pa[ks], oacc[dn], 0, 0, 0);
                }
            }
        }
        __syncthreads();
        cur ^= 1;
    }
    // ---- normalize + store: lane owns q = qg; d = dn*32 + u*8 + 4hi + j ----
    const float inv = 1.0f / l_run;
    const size_t obase = qrow * 2048 + h * 128;
    #pragma unroll
    for (int dn = 0; dn < 4; ++dn)
        #pragma unroll
        for (int u = 0; u < 4; ++u) {
            s16x4 o;
            #pragma unroll
            for (int j = 0; j < 4; ++j) o[j] = f2bf(oacc[dn][u * 4 + j] * inv);
            *(s16x4*)&Oa[obase + dn * 32 + u * 8 + hi * 4] = o;
        }
#undef STAGE
}

extern "C" void kernel_launch(void* const* d_in, const int* in_sizes, int n_in,
                              void* d_out, int out_size, void* d_ws, size_t ws_size,
                              hipStream_t stream) {
    const float* x  = (const float*)d_in[0];
    const float* Wq = (const float*)d_in[1];
    const float* bq = (const float*)d_in[2];
    const float* Wk = (const float*)d_in[3];
    const float* bk = (const float*)d_in[4];
    const float* Wv = (const float*)d_in[5];
    const float* bv = (const float*)d_in[6];
    const float* Wo = (const float*)d_in[7];
    const float* bo = (const float*)d_in[8];
    float* out = (float*)d_out;

    // ws (80 MiB): Xb [0,32M) -> WoT reuse; Qb [32M,64M) (attn in-place); Kb [64M,72M); Vt [72M,80M)
    char* ws = (char*)d_ws;
    short* Xb  = (short*)(ws);
    short* Qb  = (short*)(ws + (size_t)33554432);
    short* Kb  = (short*)(ws + (size_t)67108864);
    short* Vt  = (short*)(ws + (size_t)75497472);
    short* WoT = (short*)(ws);                      // after Xb dead
    char* dob = (char*)d_out;                       // d_out as scratch until final GEMM
    short* WqT = (short*)(dob);
    short* WkT = (short*)(dob + (size_t)8388608);
    short* WvT = (short*)(dob + (size_t)10485760);

    const int M = 8192, D = 2048;

    convert_bf16<<<dim3((M * D) / (256 * 8)), 256, 0, stream>>>(x, Xb);
    tconv<<<dim3(64, 64), 256, 0, stream>>>(Wq, WqT, D, D);
    tconv<<<dim3(64, 16), 256, 0, stream>>>(Wk, WkT, D, 512);
    tconv<<<dim3(64, 16), 256, 0, stream>>>(Wv, WvT, D, 512);

    gemm_bt<1><<<dim3(16, 64), 256, 0, stream>>>(Xb, WqT, bq, Qb, M, 2048, D);
    gemm_bt<1><<<dim3(4,  64), 256, 0, stream>>>(Xb, WkT, bk, Kb, M, 512, D);
    gemm_bt<2><<<dim3(4,  64), 256, 0, stream>>>(Xb, WvT, bv, Vt, M, 512, D);

    tconv<<<dim3(64, 64), 256, 0, stream>>>(Wo, WoT, D, D);

    attn_kernel<<<dim3(512), 512, 0, stream>>>(Qb, Kb, Vt, Qb);

    gemm_bt<0><<<dim3(16, 64), 256, 0, stream>>>(Qb, WoT, bo, out, M, 2048, D);
}

// Round 6
// 395.920 us; speedup vs baseline: 2.5086x; 1.1101x over previous
//
#include <hip/hip_runtime.h>
#include <hip/hip_bf16.h>

typedef __attribute__((ext_vector_type(4)))  float f32x4;
typedef __attribute__((ext_vector_type(16))) float f32x16;
typedef __attribute__((ext_vector_type(8)))  short s16x8;
typedef __attribute__((ext_vector_type(4)))  short s16x4;
typedef __attribute__((ext_vector_type(4)))  float fvec4;

__device__ __forceinline__ short f2bf(float f) {
    union { float f; unsigned u; } x; x.f = f;
    unsigned r = x.u + 0x7fffu + ((x.u >> 16) & 1u);
    return (short)(r >> 16);
}

__device__ __forceinline__ void gload_lds16(const short* g, short* lds) {
    __builtin_amdgcn_global_load_lds(
        (const __attribute__((address_space(1))) void*)g,
        (__attribute__((address_space(3))) void*)lds, 16, 0, 0);
}

// ---------------- fp32 -> bf16 elementwise convert ----------------
__global__ __launch_bounds__(256) void convert_bf16(const float* __restrict__ X,
                                                    short* __restrict__ Y) {
    size_t i = ((size_t)blockIdx.x * 256 + threadIdx.x) * 8;
    fvec4 a = *(const fvec4*)&X[i];
    fvec4 b = *(const fvec4*)&X[i + 4];
    s16x8 o;
    o[0] = f2bf(a[0]); o[1] = f2bf(a[1]); o[2] = f2bf(a[2]); o[3] = f2bf(a[3]);
    o[4] = f2bf(b[0]); o[5] = f2bf(b[1]); o[6] = f2bf(b[2]); o[7] = f2bf(b[3]);
    *(s16x8*)&Y[i] = o;
}

// ---------------- fp32 [K][N] -> bf16 [N][K] transpose+convert ----------------
__global__ __launch_bounds__(256) void tconv(const float* __restrict__ W,
                                             short* __restrict__ Wt,
                                             int K, int N) {
    __shared__ float tile[32][33];
    const int k0 = blockIdx.x * 32, n0 = blockIdx.y * 32;
    const int tx = threadIdx.x & 31, ty = threadIdx.x >> 5;
    #pragma unroll
    for (int i = 0; i < 4; ++i) {
        int k = ty + i * 8;
        tile[k][tx] = W[(size_t)(k0 + k) * N + n0 + tx];
    }
    __syncthreads();
    #pragma unroll
    for (int i = 0; i < 4; ++i) {
        int n = ty + i * 8;
        Wt[(size_t)(n0 + n) * K + k0 + tx] = f2bf(tile[tx][n]);
    }
}

// ---------------- GEMM 128x128 (m97): C[M,N] = A @ Bt^T + bias ----------------
// MODE 1: bf16 C row-major; 2: bf16 V-transposed epilogue
template<int MODE>
__global__ __launch_bounds__(256) void gemm_bt(const short* __restrict__ A,
                                               const short* __restrict__ Bt,
                                               const float* __restrict__ bias,
                                               void* __restrict__ Cv,
                                               int M, int N, int K) {
    __shared__ __align__(16) short As[128 * 64];
    __shared__ __align__(16) short Bs[128 * 64];
    const int tid = threadIdx.x, lane = tid & 63, wid = tid >> 6;
    const int wr = wid >> 1, wc = wid & 1;
    const int lr = lane & 15, g = lane >> 4;
    const int m0 = blockIdx.y * 128, n0 = blockIdx.x * 128;
    const int r8 = lane >> 3, c8 = lane & 7;

    f32x4 acc[4][4] = {};

    const short* ga = A  + (size_t)(m0 + wid * 8 + r8) * K + c8 * 8;
    const short* gb = Bt + (size_t)(n0 + wid * 8 + r8) * K + c8 * 8;

    for (int k0 = 0; k0 < K; k0 += 64) {
        #pragma unroll
        for (int it = 0; it < 4; ++it) {
            gload_lds16(ga + (size_t)(it * 32) * K + k0, &As[(wid * 8 + it * 32) * 64]);
            gload_lds16(gb + (size_t)(it * 32) * K + k0, &Bs[(wid * 8 + it * 32) * 64]);
        }
        __syncthreads();
        #pragma unroll
        for (int kk = 0; kk < 2; ++kk) {
            s16x8 af[4], bfv[4];
            #pragma unroll
            for (int m = 0; m < 4; ++m)
                af[m] = *(const s16x8*)&As[(wr * 64 + m * 16 + lr) * 64 + kk * 32 + g * 8];
            #pragma unroll
            for (int n = 0; n < 4; ++n)
                bfv[n] = *(const s16x8*)&Bs[(wc * 64 + n * 16 + lr) * 64 + kk * 32 + g * 8];
            #pragma unroll
            for (int m = 0; m < 4; ++m)
                #pragma unroll
                for (int n = 0; n < 4; ++n)
                    acc[m][n] = __builtin_amdgcn_mfma_f32_16x16x32_bf16(af[m], bfv[n], acc[m][n], 0, 0, 0);
        }
        __syncthreads();
    }
    #pragma unroll
    for (int m = 0; m < 4; ++m) {
        if constexpr (MODE == 2) {
            #pragma unroll
            for (int n = 0; n < 4; ++n) {
                int col = n0 + wc * 64 + n * 16 + lr;       // 0..511
                int kvh = col >> 7, d = col & 127;
                int row0 = m0 + wr * 64 + m * 16 + g * 4;
                int b = row0 >> 11, s0 = row0 & 2047;
                s16x4 o;
                #pragma unroll
                for (int j = 0; j < 4; ++j) o[j] = f2bf(acc[m][n][j] + bias[col]);
                *(s16x4*)&((short*)Cv)[(((size_t)b * 4 + kvh) * 128 + d) * 2048 + s0] = o;
            }
        } else {
            #pragma unroll
            for (int j = 0; j < 4; ++j) {
                int row = m0 + wr * 64 + m * 16 + g * 4 + j;
                #pragma unroll
                for (int n = 0; n < 4; ++n) {
                    int col = n0 + wc * 64 + n * 16 + lr;
                    float v = acc[m][n][j] + bias[col];
                    ((short*)Cv)[(size_t)row * N + col] = f2bf(v);
                }
            }
        }
    }
}

// ---------------- GEMM 256x256 phase-pipelined (counted vmcnt) ----------------
// MODE 0: f32 C; 1: bf16 C. 512 threads, 8 waves (2Mx4N), BK=64, 128 KiB LDS.
// Schedule: all 8 global_load_lds for tile T+1 issued at tile T's phase 1;
// gate = s_waitcnt vmcnt(8) (keeps T+1's 8 in flight, waits tile T landed)
// + s_barrier. 4 phases/tile, 16 MFMA each, T2 XOR-swizzled LDS.
template<int MODE>
__global__ __launch_bounds__(512, 1) void gemm256(const short* __restrict__ A,
                                                  const short* __restrict__ Bt,
                                                  const float* __restrict__ bias,
                                                  void* __restrict__ Cv,
                                                  int M, int N, int K) {
    __shared__ __align__(16) short As[2][16384];   // [dbuf][256 rows][64 k] swizzled
    __shared__ __align__(16) short Bs[2][16384];
    const int tid = threadIdx.x, lane = tid & 63, w = tid >> 6;
    const int wr = w >> 2, wc = w & 3;
    const int lr = lane & 15, g = lane >> 4;
    const int m0 = blockIdx.y * 256, n0 = blockIdx.x * 256;
    const int r0 = w * 8 + (lane >> 3);                       // staging row (0..63 per issue)
    const int sw = ((lane & 7) ^ ((lane >> 3) & 7)) * 8;      // pre-swizzled global k-slot
    const int swr = lr & 7;                                   // read-side row-XOR

    const short* ga = A  + (size_t)(m0 + r0) * K + sw;
    const short* gb = Bt + (size_t)(n0 + r0) * K + sw;
    const int lbase = r0 * 64 - (lane & 7) * 8;               // wave-uniform-ish base: HW adds lane*16B

    f32x4 acc[8][4] = {};
    const int NT = K >> 6;

#define STAGE256(d, t) do {                                                     \
    const int kk0_ = (t) << 6;                                                  \
    _Pragma("unroll")                                                           \
    for (int it_ = 0; it_ < 4; ++it_) {                                         \
        gload_lds16(ga + (size_t)(it_ * 64) * K + kk0_, &As[d][it_ * 4096 + w * 512]); \
        gload_lds16(gb + (size_t)(it_ * 64) * K + kk0_, &Bs[d][it_ * 4096 + w * 512]); \
    }                                                                           \
} while (0)

    STAGE256(0, 0);

    for (int T = 0; T < NT; ++T) {
        const int d = T & 1;
        if (T + 1 < NT) {
            STAGE256((T + 1) & 1, T + 1);
            asm volatile("s_waitcnt vmcnt(8)" ::: "memory");
        } else {
            asm volatile("s_waitcnt vmcnt(0)" ::: "memory");
        }
        __builtin_amdgcn_s_barrier();        // all waves' tile-T data resident
        __builtin_amdgcn_sched_barrier(0);
        // B fragments for the whole tile (register-cached across phases)
        s16x8 bf[4][2];
        #pragma unroll
        for (int n = 0; n < 4; ++n)
            #pragma unroll
            for (int kk = 0; kk < 2; ++kk)
                bf[n][kk] = *(const s16x8*)&Bs[d][(wc * 64 + n * 16 + lr) * 64 +
                                                 (((kk << 2) | g) ^ swr) * 8];
        #pragma unroll
        for (int p = 0; p < 4; ++p) {
            s16x8 af[2][2];
            #pragma unroll
            for (int mm = 0; mm < 2; ++mm)
                #pragma unroll
                for (int kk = 0; kk < 2; ++kk)
                    af[mm][kk] = *(const s16x8*)&As[d][(wr * 128 + (p * 2 + mm) * 16 + lr) * 64 +
                                                      (((kk << 2) | g) ^ swr) * 8];
            __builtin_amdgcn_s_setprio(1);
            #pragma unroll
            for (int kk = 0; kk < 2; ++kk)
                #pragma unroll
                for (int mm = 0; mm < 2; ++mm)
                    #pragma unroll
                    for (int n = 0; n < 4; ++n)
                        acc[p * 2 + mm][n] = __builtin_amdgcn_mfma_f32_16x16x32_bf16(
                            af[mm][kk], bf[n][kk], acc[p * 2 + mm][n], 0, 0, 0);
            __builtin_amdgcn_s_setprio(0);
            __builtin_amdgcn_s_barrier();
        }
        __builtin_amdgcn_sched_barrier(0);
    }
    (void)lbase;
    // ---- epilogue ----
    #pragma unroll
    for (int m = 0; m < 8; ++m)
        #pragma unroll
        for (int j = 0; j < 4; ++j) {
            int row = m0 + wr * 128 + m * 16 + g * 4 + j;
            #pragma unroll
            for (int n = 0; n < 4; ++n) {
                int col = n0 + wc * 64 + n * 16 + lr;
                float v = acc[m][n][j] + bias[col];
                if constexpr (MODE == 1) ((short*)Cv)[(size_t)row * N + col] = f2bf(v);
                else                     ((float*)Cv)[(size_t)row * N + col] = v;
            }
        }
#undef STAGE256
}

// ---------------- Flash attention: 8 waves x 32 q-rows, KVBLK=64, 32x32x16 ----
__global__ __launch_bounds__(512, 1) void attn_kernel(const short* __restrict__ Q,
                                                      const short* __restrict__ Kg,
                                                      const short* __restrict__ Vtg,
                                                      short* __restrict__ Oa) {
    __shared__ __align__(16) short Klds[2][8192];   // [64 kv][128 d], 16B-slot XOR-swizzled
    __shared__ __align__(16) short Vlds[2][8192];   // [128 d][64 kv], swizzled
    __shared__ __align__(16) short Plds[8][32][72]; // per-wave P [q][kv], pad 8
    const int tid = threadIdx.x;
    const int lane = tid & 63, w = tid >> 6;
    const int l31 = lane & 31, hi = lane >> 5, e7 = lane & 7;
    const int ve = hi ^ e7;

    const int bid = blockIdx.x;
    const int phase = bid >> 8, idx = bid & 255;
    const int bh = idx >> 2;
    const int b = bh >> 4, h = bh & 15;
    const int qt = phase ? (3 - (idx & 3)) : (4 + (idx & 3));
    const int qb = qt << 8;
    const int kvh = h >> 2;
    const float scale = 0.08838834764831845f;   // 1/sqrt(128)

    const int q_min = qb + w * 32;
    const int qg = q_min + l31;
    const size_t qrow = (size_t)b * 2048 + qg;

    s16x8 qf[8];
    #pragma unroll
    for (int c = 0; c < 8; ++c)
        qf[c] = *(const s16x8*)&Q[qrow * 2048 + h * 128 + c * 16 + hi * 8];

    f32x16 oacc[4] = {};
    float m_run = -1e28f, l_run = 0.f;

    const int nt = (qb >> 6) + 4;
    const int tp_w = q_min >> 6;

    const short* Kbase = Kg + ((size_t)b * 2048) * 512 + kvh * 128;
    const short* Vbase = Vtg + ((size_t)(b * 4 + kvh)) * 128 * 2048;

    const int krow0 = w * 4 + (lane >> 4), kslot = lane & 15;
    const int vrow0 = w * 8 + (lane >> 3), vslot = lane & 7;

#define STAGE(buf, t) do {                                                        \
    const int kv0_ = (t) << 6;                                                    \
    _Pragma("unroll")                                                             \
    for (int s_ = 0; s_ < 2; ++s_) {                                              \
        int kr = s_ * 32 + krow0;                                                 \
        gload_lds16(Kbase + (size_t)(kv0_ + kr) * 512 + (kslot ^ (kr & 7)) * 8,   \
                    &Klds[buf][s_ * 4096 + w * 512]);                             \
        int vr = s_ * 64 + vrow0;                                                 \
        gload_lds16(Vbase + (size_t)vr * 2048 + kv0_ + (vslot ^ (vr & 7)) * 8,    \
                    &Vlds[buf][s_ * 4096 + w * 512]);                             \
    }                                                                             \
} while (0)

    STAGE(0, 0);
    __syncthreads();

    int cur = 0;
    for (int t = 0; t < nt; ++t) {
        if (t + 1 < nt) STAGE(cur ^ 1, t + 1);
        if (t <= tp_w) {
            f32x16 s0 = {}, s1 = {};
            const short* kb = &Klds[cur][l31 * 128];
            #pragma unroll
            for (int c = 0; c < 8; ++c) {
                int sl = (((c << 1) ^ ve)) * 8;
                s16x8 kf0 = *(const s16x8*)&kb[sl];
                s16x8 kf1 = *(const s16x8*)&kb[4096 + sl];
                s0 = __builtin_amdgcn_mfma_f32_32x32x16_bf16(kf0, qf[c], s0, 0, 0, 0);
                s1 = __builtin_amdgcn_mfma_f32_32x32x16_bf16(kf1, qf[c], s1, 0, 0, 0);
            }
            if (t == tp_w) {
                const int qrel = qg - (t << 6) - 4 * hi;
                #pragma unroll
                for (int r = 0; r < 16; ++r) {
                    const int rw = (r & 3) + 8 * (r >> 2);
                    if (rw > qrel)      s0[r] = -1e30f;
                    if (rw + 32 > qrel) s1[r] = -1e30f;
                }
            }
            float mx[16];
            #pragma unroll
            for (int r = 0; r < 16; ++r) mx[r] = fmaxf(s0[r], s1[r]);
            #pragma unroll
            for (int d = 8; d >= 1; d >>= 1)
                #pragma unroll
                for (int r = 0; r < d; ++r) mx[r] = fmaxf(mx[r], mx[r + d]);
            float pmax = mx[0];
            pmax = fmaxf(pmax, __shfl_xor(pmax, 32));
            if (!__all(pmax <= m_run + 90.5f)) {
                float mn = fmaxf(m_run, pmax);
                float fs = __expf((m_run - mn) * scale);
                l_run *= fs;
                #pragma unroll
                for (int dn = 0; dn < 4; ++dn)
                    #pragma unroll
                    for (int r = 0; r < 16; ++r) oacc[dn][r] *= fs;
                m_run = mn;
            }
            const float mb = m_run * scale;
            float psum = 0.f;
            #pragma unroll
            for (int r = 0; r < 16; ++r) {
                s0[r] = __expf(fmaf(s0[r], scale, -mb));
                s1[r] = __expf(fmaf(s1[r], scale, -mb));
                psum += s0[r] + s1[r];
            }
            l_run += psum + __shfl_xor(psum, 32);
            short* Pw = (short*)&Plds[w][0][0];
            #pragma unroll
            for (int u = 0; u < 4; ++u) {
                s16x4 w0, w1;
                #pragma unroll
                for (int j = 0; j < 4; ++j) { w0[j] = f2bf(s0[4*u+j]); w1[j] = f2bf(s1[4*u+j]); }
                *(s16x4*)&Pw[l31 * 72 + u * 8 + hi * 4]      = w0;
                *(s16x4*)&Pw[l31 * 72 + 32 + u * 8 + hi * 4] = w1;
            }
            asm volatile("s_waitcnt lgkmcnt(0)" ::: "memory");
            __builtin_amdgcn_sched_barrier(0);
            s16x8 pa[4];
            #pragma unroll
            for (int ks = 0; ks < 4; ++ks)
                pa[ks] = *(const s16x8*)&Pw[l31 * 72 + ks * 16 + hi * 8];
            const short* vb = &Vlds[cur][l31 * 64];
            #pragma unroll
            for (int ks = 0; ks < 4; ++ks) {
                int sl = (((ks << 1) ^ ve)) * 8;
                #pragma unroll
                for (int dn = 0; dn < 4; ++dn) {
                    s16x8 vf = *(const s16x8*)&vb[dn * 2048 + sl];
                    oacc[dn] = __builtin_amdgcn_mfma_f32_32x32x16_bf16(vf, pa[ks], oacc[dn], 0, 0, 0);
                }
            }
        }
        __syncthreads();
        cur ^= 1;
    }
    const float inv = 1.0f / l_run;
    const size_t obase = qrow * 2048 + h * 128;
    #pragma unroll
    for (int dn = 0; dn < 4; ++dn)
        #pragma unroll
        for (int u = 0; u < 4; ++u) {
            s16x4 o;
            #pragma unroll
            for (int j = 0; j < 4; ++j) o[j] = f2bf(oacc[dn][u * 4 + j] * inv);
            *(s16x4*)&Oa[obase + dn * 32 + u * 8 + hi * 4] = o;
        }
#undef STAGE
}

extern "C" void kernel_launch(void* const* d_in, const int* in_sizes, int n_in,
                              void* d_out, int out_size, void* d_ws, size_t ws_size,
                              hipStream_t stream) {
    const float* x  = (const float*)d_in[0];
    const float* Wq = (const float*)d_in[1];
    const float* bq = (const float*)d_in[2];
    const float* Wk = (const float*)d_in[3];
    const float* bk = (const float*)d_in[4];
    const float* Wv = (const float*)d_in[5];
    const float* bv = (const float*)d_in[6];
    const float* Wo = (const float*)d_in[7];
    const float* bo = (const float*)d_in[8];
    float* out = (float*)d_out;

    // ws (80 MiB): Xb [0,32M) -> WoT reuse; Qb [32M,64M) (attn in-place); Kb [64M,72M); Vt [72M,80M)
    char* ws = (char*)d_ws;
    short* Xb  = (short*)(ws);
    short* Qb  = (short*)(ws + (size_t)33554432);
    short* Kb  = (short*)(ws + (size_t)67108864);
    short* Vt  = (short*)(ws + (size_t)75497472);
    short* WoT = (short*)(ws);                      // after Xb dead
    char* dob = (char*)d_out;                       // d_out as scratch until final GEMM
    short* WqT = (short*)(dob);
    short* WkT = (short*)(dob + (size_t)8388608);
    short* WvT = (short*)(dob + (size_t)10485760);

    const int M = 8192, D = 2048;

    convert_bf16<<<dim3((M * D) / (256 * 8)), 256, 0, stream>>>(x, Xb);
    tconv<<<dim3(64, 64), 256, 0, stream>>>(Wq, WqT, D, D);
    tconv<<<dim3(64, 16), 256, 0, stream>>>(Wk, WkT, D, 512);
    tconv<<<dim3(64, 16), 256, 0, stream>>>(Wv, WvT, D, 512);

    gemm256<1><<<dim3(8, 32), 512, 0, stream>>>(Xb, WqT, bq, Qb, M, 2048, D);
    gemm_bt<1><<<dim3(4, 64), 256, 0, stream>>>(Xb, WkT, bk, Kb, M, 512, D);
    gemm_bt<2><<<dim3(4, 64), 256, 0, stream>>>(Xb, WvT, bv, Vt, M, 512, D);

    tconv<<<dim3(64, 64), 256, 0, stream>>>(Wo, WoT, D, D);

    attn_kernel<<<dim3(512), 512, 0, stream>>>(Qb, Kb, Vt, Qb);

    gemm256<0><<<dim3(8, 32), 512, 0, stream>>>(Qb, WoT, bo, out, M, 2048, D);
}

// Round 8
// 387.754 us; speedup vs baseline: 2.5614x; 1.0211x over previous
//
#include <hip/hip_runtime.h>
#include <hip/hip_bf16.h>

typedef __attribute__((ext_vector_type(4)))  float f32x4;
typedef __attribute__((ext_vector_type(16))) float f32x16;
typedef __attribute__((ext_vector_type(8)))  short s16x8;
typedef __attribute__((ext_vector_type(4)))  short s16x4;
typedef __attribute__((ext_vector_type(4)))  float fvec4;

__device__ __forceinline__ short f2bf(float f) {
    union { float f; unsigned u; } x; x.f = f;
    unsigned r = x.u + 0x7fffu + ((x.u >> 16) & 1u);
    return (short)(r >> 16);
}

__device__ __forceinline__ void gload_lds16(const short* g, short* lds) {
    __builtin_amdgcn_global_load_lds(
        (const __attribute__((address_space(1))) void*)g,
        (__attribute__((address_space(3))) void*)lds, 16, 0, 0);
}

// ---------------- fp32 -> bf16 elementwise convert ----------------
__global__ __launch_bounds__(256) void convert_bf16(const float* __restrict__ X,
                                                    short* __restrict__ Y) {
    size_t i = ((size_t)blockIdx.x * 256 + threadIdx.x) * 8;
    fvec4 a = *(const fvec4*)&X[i];
    fvec4 b = *(const fvec4*)&X[i + 4];
    s16x8 o;
    o[0] = f2bf(a[0]); o[1] = f2bf(a[1]); o[2] = f2bf(a[2]); o[3] = f2bf(a[3]);
    o[4] = f2bf(b[0]); o[5] = f2bf(b[1]); o[6] = f2bf(b[2]); o[7] = f2bf(b[3]);
    *(s16x8*)&Y[i] = o;
}

// ---------------- fp32 [K][N] -> bf16 [N][K] transpose+convert ----------------
__global__ __launch_bounds__(256) void tconv(const float* __restrict__ W,
                                             short* __restrict__ Wt,
                                             int K, int N) {
    __shared__ float tile[32][33];
    const int k0 = blockIdx.x * 32, n0 = blockIdx.y * 32;
    const int tx = threadIdx.x & 31, ty = threadIdx.x >> 5;
    #pragma unroll
    for (int i = 0; i < 4; ++i) {
        int k = ty + i * 8;
        tile[k][tx] = W[(size_t)(k0 + k) * N + n0 + tx];
    }
    __syncthreads();
    #pragma unroll
    for (int i = 0; i < 4; ++i) {
        int n = ty + i * 8;
        Wt[(size_t)(n0 + n) * K + k0 + tx] = f2bf(tile[tx][n]);
    }
}

// ---------------- GEMM 128x128 (m97): C[M,N] = A @ Bt^T + bias ----------------
// MODE 1: bf16 C row-major; 2: bf16 V-transposed epilogue (kv bits 2<->3 swapped)
template<int MODE>
__global__ __launch_bounds__(256) void gemm_bt(const short* __restrict__ A,
                                               const short* __restrict__ Bt,
                                               const float* __restrict__ bias,
                                               void* __restrict__ Cv,
                                               int M, int N, int K) {
    __shared__ __align__(16) short As[128 * 64];
    __shared__ __align__(16) short Bs[128 * 64];
    const int tid = threadIdx.x, lane = tid & 63, wid = tid >> 6;
    const int wr = wid >> 1, wc = wid & 1;
    const int lr = lane & 15, g = lane >> 4;
    const int m0 = blockIdx.y * 128, n0 = blockIdx.x * 128;
    const int r8 = lane >> 3, c8 = lane & 7;

    f32x4 acc[4][4] = {};

    const short* ga = A  + (size_t)(m0 + wid * 8 + r8) * K + c8 * 8;
    const short* gb = Bt + (size_t)(n0 + wid * 8 + r8) * K + c8 * 8;

    for (int k0 = 0; k0 < K; k0 += 64) {
        #pragma unroll
        for (int it = 0; it < 4; ++it) {
            gload_lds16(ga + (size_t)(it * 32) * K + k0, &As[(wid * 8 + it * 32) * 64]);
            gload_lds16(gb + (size_t)(it * 32) * K + k0, &Bs[(wid * 8 + it * 32) * 64]);
        }
        __syncthreads();
        #pragma unroll
        for (int kk = 0; kk < 2; ++kk) {
            s16x8 af[4], bfv[4];
            #pragma unroll
            for (int m = 0; m < 4; ++m)
                af[m] = *(const s16x8*)&As[(wr * 64 + m * 16 + lr) * 64 + kk * 32 + g * 8];
            #pragma unroll
            for (int n = 0; n < 4; ++n)
                bfv[n] = *(const s16x8*)&Bs[(wc * 64 + n * 16 + lr) * 64 + kk * 32 + g * 8];
            #pragma unroll
            for (int m = 0; m < 4; ++m)
                #pragma unroll
                for (int n = 0; n < 4; ++n)
                    acc[m][n] = __builtin_amdgcn_mfma_f32_16x16x32_bf16(af[m], bfv[n], acc[m][n], 0, 0, 0);
        }
        __syncthreads();
    }
    #pragma unroll
    for (int m = 0; m < 4; ++m) {
        if constexpr (MODE == 2) {
            #pragma unroll
            for (int n = 0; n < 4; ++n) {
                int col = n0 + wc * 64 + n * 16 + lr;       // 0..511
                int kvh = col >> 7, d = col & 127;
                int row0 = m0 + wr * 64 + m * 16 + g * 4;
                int b = row0 >> 11, s0 = row0 & 2047;
                // kv-axis permutation sigma: swap bits 2<->3 (self-inverse).
                // Lets attention feed P to the PV MFMA in native C/D register
                // order with no cross-lane exchange.
                int s0p = (s0 & ~15) | (((s0 >> 2) & 1) << 3) | (((s0 >> 3) & 1) << 2);
                s16x4 o;
                #pragma unroll
                for (int j = 0; j < 4; ++j) o[j] = f2bf(acc[m][n][j] + bias[col]);
                *(s16x4*)&((short*)Cv)[(((size_t)b * 4 + kvh) * 128 + d) * 2048 + s0p] = o;
            }
        } else {
            #pragma unroll
            for (int j = 0; j < 4; ++j) {
                int row = m0 + wr * 64 + m * 16 + g * 4 + j;
                #pragma unroll
                for (int n = 0; n < 4; ++n) {
                    int col = n0 + wc * 64 + n * 16 + lr;
                    float v = acc[m][n][j] + bias[col];
                    ((short*)Cv)[(size_t)row * N + col] = f2bf(v);
                }
            }
        }
    }
}

// ---------------- GEMM 256x256 phase-pipelined (counted vmcnt) ----------------
template<int MODE>
__global__ __launch_bounds__(512, 1) void gemm256(const short* __restrict__ A,
                                                  const short* __restrict__ Bt,
                                                  const float* __restrict__ bias,
                                                  void* __restrict__ Cv,
                                                  int M, int N, int K) {
    __shared__ __align__(16) short As[2][16384];   // [dbuf][256 rows][64 k] swizzled
    __shared__ __align__(16) short Bs[2][16384];
    const int tid = threadIdx.x, lane = tid & 63, w = tid >> 6;
    const int wr = w >> 2, wc = w & 3;
    const int lr = lane & 15, g = lane >> 4;
    const int m0 = blockIdx.y * 256, n0 = blockIdx.x * 256;
    const int r0 = w * 8 + (lane >> 3);
    const int sw = ((lane & 7) ^ ((lane >> 3) & 7)) * 8;
    const int swr = lr & 7;

    const short* ga = A  + (size_t)(m0 + r0) * K + sw;
    const short* gb = Bt + (size_t)(n0 + r0) * K + sw;

    f32x4 acc[8][4] = {};
    const int NT = K >> 6;

#define STAGE256(d, t) do {                                                     \
    const int kk0_ = (t) << 6;                                                  \
    _Pragma("unroll")                                                           \
    for (int it_ = 0; it_ < 4; ++it_) {                                         \
        gload_lds16(ga + (size_t)(it_ * 64) * K + kk0_, &As[d][it_ * 4096 + w * 512]); \
        gload_lds16(gb + (size_t)(it_ * 64) * K + kk0_, &Bs[d][it_ * 4096 + w * 512]); \
    }                                                                           \
} while (0)

    STAGE256(0, 0);

    for (int T = 0; T < NT; ++T) {
        const int d = T & 1;
        if (T + 1 < NT) {
            STAGE256((T + 1) & 1, T + 1);
            asm volatile("s_waitcnt vmcnt(8)" ::: "memory");
        } else {
            asm volatile("s_waitcnt vmcnt(0)" ::: "memory");
        }
        __builtin_amdgcn_s_barrier();
        __builtin_amdgcn_sched_barrier(0);
        s16x8 bf[4][2];
        #pragma unroll
        for (int n = 0; n < 4; ++n)
            #pragma unroll
            for (int kk = 0; kk < 2; ++kk)
                bf[n][kk] = *(const s16x8*)&Bs[d][(wc * 64 + n * 16 + lr) * 64 +
                                                 (((kk << 2) | g) ^ swr) * 8];
        #pragma unroll
        for (int p = 0; p < 4; ++p) {
            s16x8 af[2][2];
            #pragma unroll
            for (int mm = 0; mm < 2; ++mm)
                #pragma unroll
                for (int kk = 0; kk < 2; ++kk)
                    af[mm][kk] = *(const s16x8*)&As[d][(wr * 128 + (p * 2 + mm) * 16 + lr) * 64 +
                                                      (((kk << 2) | g) ^ swr) * 8];
            __builtin_amdgcn_s_setprio(1);
            #pragma unroll
            for (int kk = 0; kk < 2; ++kk)
                #pragma unroll
                for (int mm = 0; mm < 2; ++mm)
                    #pragma unroll
                    for (int n = 0; n < 4; ++n)
                        acc[p * 2 + mm][n] = __builtin_amdgcn_mfma_f32_16x16x32_bf16(
                            af[mm][kk], bf[n][kk], acc[p * 2 + mm][n], 0, 0, 0);
            __builtin_amdgcn_s_setprio(0);
            __builtin_amdgcn_s_barrier();
        }
        __builtin_amdgcn_sched_barrier(0);
    }
    #pragma unroll
    for (int m = 0; m < 8; ++m)
        #pragma unroll
        for (int j = 0; j < 4; ++j) {
            int row = m0 + wr * 128 + m * 16 + g * 4 + j;
            #pragma unroll
            for (int n = 0; n < 4; ++n) {
                int col = n0 + wc * 64 + n * 16 + lr;
                float v = acc[m][n][j] + bias[col];
                if constexpr (MODE == 1) ((short*)Cv)[(size_t)row * N + col] = f2bf(v);
                else                     ((float*)Cv)[(size_t)row * N + col] = v;
            }
        }
#undef STAGE256
}

// ---------------- Flash attention: 8 waves x 32 q-rows, KVBLK=64, 32x32x16 ----
// In-register softmax; P feeds PV in native C/D order (V kv-axis pre-permuted
// by the projection epilogue: sigma = swap kv bits 2<->3). No cross-lane P ops.
#define SC2 0.12751743f   // (1/sqrt(128)) * log2(e)

__global__ __launch_bounds__(512, 1) void attn_kernel(const short* __restrict__ Q,
                                                      const short* __restrict__ Kg,
                                                      const short* __restrict__ Vtg,
                                                      short* __restrict__ Oa) {
    __shared__ __align__(16) short Klds[2][8192];   // [64 kv][128 d], 16B-slot XOR-swizzled
    __shared__ __align__(16) short Vlds[2][8192];   // [128 d][64 kv(perm)], swizzled
    const int tid = threadIdx.x;
    const int lane = tid & 63, w = tid >> 6;
    const int l31 = lane & 31, hi = lane >> 5, e7 = lane & 7;
    const int ve = hi ^ e7;

    const int bid = blockIdx.x;
    const int phase = bid >> 8, idx = bid & 255;
    const int bh = idx >> 2;
    const int b = bh >> 4, h = bh & 15;
    const int qt = phase ? (3 - (idx & 3)) : (4 + (idx & 3));
    const int qb = qt << 8;
    const int kvh = h >> 2;

    const int q_min = qb + w * 32;
    const int qg = q_min + l31;
    const size_t qrow = (size_t)b * 2048 + qg;

    s16x8 qf[8];
    #pragma unroll
    for (int c = 0; c < 8; ++c)
        qf[c] = *(const s16x8*)&Q[qrow * 2048 + h * 128 + c * 16 + hi * 8];

    f32x16 oacc[4] = {};
    // m_run init must stay >> mask value (-1e30) so fully-masked rows give p=0.
    float m_run = -1e28f, l_run = 0.f;

    const int nt = (qb >> 6) + 4;

    const short* Kbase = Kg + ((size_t)b * 2048) * 512 + kvh * 128;
    const short* Vbase = Vtg + ((size_t)(b * 4 + kvh)) * 128 * 2048;

    const int krow0 = w * 4 + (lane >> 4), kslot = lane & 15;
    const int vrow0 = w * 8 + (lane >> 3), vslot = lane & 7;

#define STAGE(buf, t) do {                                                        \
    const int kv0_ = (t) << 6;                                                    \
    _Pragma("unroll")                                                             \
    for (int s_ = 0; s_ < 2; ++s_) {                                              \
        int kr = s_ * 32 + krow0;                                                 \
        gload_lds16(Kbase + (size_t)(kv0_ + kr) * 512 + (kslot ^ (kr & 7)) * 8,   \
                    &Klds[buf][s_ * 4096 + w * 512]);                             \
        int vr = s_ * 64 + vrow0;                                                 \
        gload_lds16(Vbase + (size_t)vr * 2048 + kv0_ + (vslot ^ (vr & 7)) * 8,    \
                    &Vlds[buf][s_ * 4096 + w * 512]);                             \
    }                                                                             \
} while (0)

    STAGE(0, 0);
    __syncthreads();

    int cur = 0;
    for (int t = 0; t < nt; ++t) {
        if (t + 1 < nt) STAGE(cur ^ 1, t + 1);
        #pragma unroll
        for (int st = 0; st < 2; ++st) {
            const int kvoff = (t << 6) + (st << 5);
            if (kvoff > q_min) break;       // wave-uniform: subtile beyond diagonal
            // ---- S^T = K Q^T for this 32-kv subtile ----
            f32x16 s = {};
            const short* kb = &Klds[cur][((st << 5) + l31) * 128];
            #pragma unroll
            for (int c = 0; c < 8; ++c) {
                s16x8 kf = *(const s16x8*)&kb[(((c << 1) ^ ve)) * 8];
                s = __builtin_amdgcn_mfma_f32_32x32x16_bf16(kf, qf[c], s, 0, 0, 0);
            }
            // ---- causal mask (only on the diagonal subtile) ----
            if (kvoff == q_min) {
                #pragma unroll
                for (int r = 0; r < 16; ++r) {
                    const int rw = (r & 3) + 8 * (r >> 2) + 4 * hi;
                    if (rw > l31) s[r] = -1e30f;
                }
            }
            // ---- in-register softmax (q = lane&31 across both halves) ----
            float m01 = fmaxf(s[0], s[1]),   m23 = fmaxf(s[2], s[3]);
            float m45 = fmaxf(s[4], s[5]),   m67 = fmaxf(s[6], s[7]);
            float m89 = fmaxf(s[8], s[9]),   mab = fmaxf(s[10], s[11]);
            float mcd = fmaxf(s[12], s[13]), mef = fmaxf(s[14], s[15]);
            float mA = fmaxf(fmaxf(m01, m23), fmaxf(m45, m67));
            float mB = fmaxf(fmaxf(m89, mab), fmaxf(mcd, mef));
            float pm = fmaxf(mA, mB);
            pm = fmaxf(pm, __shfl_xor(pm, 32));     // combine lane/partner halves
            if (!__all(pm <= m_run + 90.5f)) {      // defer-max, thr = 8 nats
                float mn = fmaxf(m_run, pm);
                float fs = __builtin_amdgcn_exp2f((m_run - mn) * SC2);
                l_run *= fs;
                #pragma unroll
                for (int dn = 0; dn < 4; ++dn)
                    #pragma unroll
                    for (int r = 0; r < 16; ++r) oacc[dn][r] *= fs;
                m_run = mn;
            }
            const float mb2 = m_run * SC2;
            #pragma unroll
            for (int r = 0; r < 16; ++r)
                s[r] = __builtin_amdgcn_exp2f(fmaf(s[r], SC2, -mb2));
            float s01 = s[0] + s[1],   s23 = s[2] + s[3];
            float s45 = s[4] + s[5],   s67 = s[6] + s[7];
            float s89 = s[8] + s[9],   sab = s[10] + s[11];
            float scd = s[12] + s[13], sef = s[14] + s[15];
            float sAB = ((s01 + s23) + (s45 + s67)) + ((s89 + sab) + (scd + sef));
            l_run += sAB + __shfl_xor(sAB, 32);     // own + partner halves
            // ---- P -> bf16 PV fragments: native order (V pre-permuted) ----
            s16x8 pa0, pa1;
            #pragma unroll
            for (int j = 0; j < 8; ++j) { pa0[j] = f2bf(s[j]); pa1[j] = f2bf(s[8 + j]); }
            // ---- O^T += Vt P ----
            const short* vb = &Vlds[cur][l31 * 64];
            #pragma unroll
            for (int dn = 0; dn < 4; ++dn) {
                s16x8 vf = *(const s16x8*)&vb[dn * 2048 + (((st << 2) ^ ve)) * 8];
                oacc[dn] = __builtin_amdgcn_mfma_f32_32x32x16_bf16(vf, pa0, oacc[dn], 0, 0, 0);
            }
            #pragma unroll
            for (int dn = 0; dn < 4; ++dn) {
                s16x8 vf = *(const s16x8*)&vb[dn * 2048 + ((((st << 2) | 2) ^ ve)) * 8];
                oacc[dn] = __builtin_amdgcn_mfma_f32_32x32x16_bf16(vf, pa1, oacc[dn], 0, 0, 0);
            }
        }
        __syncthreads();
        cur ^= 1;
    }
    // ---- normalize + store: lane owns q = qg; d = dn*32 + u*8 + 4hi + j ----
    const float inv = 1.0f / l_run;
    const size_t obase = qrow * 2048 + h * 128;
    #pragma unroll
    for (int dn = 0; dn < 4; ++dn)
        #pragma unroll
        for (int u = 0; u < 4; ++u) {
            s16x4 o;
            #pragma unroll
            for (int j = 0; j < 4; ++j) o[j] = f2bf(oacc[dn][u * 4 + j] * inv);
            *(s16x4*)&Oa[obase + dn * 32 + u * 8 + hi * 4] = o;
        }
#undef STAGE
}

extern "C" void kernel_launch(void* const* d_in, const int* in_sizes, int n_in,
                              void* d_out, int out_size, void* d_ws, size_t ws_size,
                              hipStream_t stream) {
    const float* x  = (const float*)d_in[0];
    const float* Wq = (const float*)d_in[1];
    const float* bq = (const float*)d_in[2];
    const float* Wk = (const float*)d_in[3];
    const float* bk = (const float*)d_in[4];
    const float* Wv = (const float*)d_in[5];
    const float* bv = (const float*)d_in[6];
    const float* Wo = (const float*)d_in[7];
    const float* bo = (const float*)d_in[8];
    float* out = (float*)d_out;

    // ws (80 MiB): Xb [0,32M) -> WoT reuse; Qb [32M,64M) (attn in-place); Kb [64M,72M); Vt [72M,80M)
    char* ws = (char*)d_ws;
    short* Xb  = (short*)(ws);
    short* Qb  = (short*)(ws + (size_t)33554432);
    short* Kb  = (short*)(ws + (size_t)67108864);
    short* Vt  = (short*)(ws + (size_t)75497472);
    short* WoT = (short*)(ws);                      // after Xb dead
    char* dob = (char*)d_out;                       // d_out as scratch until final GEMM
    short* WqT = (short*)(dob);
    short* WkT = (short*)(dob + (size_t)8388608);
    short* WvT = (short*)(dob + (size_t)10485760);

    const int M = 8192, D = 2048;

    convert_bf16<<<dim3((M * D) / (256 * 8)), 256, 0, stream>>>(x, Xb);
    tconv<<<dim3(64, 64), 256, 0, stream>>>(Wq, WqT, D, D);
    tconv<<<dim3(64, 16), 256, 0, stream>>>(Wk, WkT, D, 512);
    tconv<<<dim3(64, 16), 256, 0, stream>>>(Wv, WvT, D, 512);

    gemm256<1><<<dim3(8, 32), 512, 0, stream>>>(Xb, WqT, bq, Qb, M, 2048, D);
    gemm_bt<1><<<dim3(4, 64), 256, 0, stream>>>(Xb, WkT, bk, Kb, M, 512, D);
    gemm_bt<2><<<dim3(4, 64), 256, 0, stream>>>(Xb, WvT, bv, Vt, M, 512, D);

    tconv<<<dim3(64, 64), 256, 0, stream>>>(Wo, WoT, D, D);

    attn_kernel<<<dim3(512), 512, 0, stream>>>(Qb, Kb, Vt, Qb);

    gemm256<0><<<dim3(8, 32), 512, 0, stream>>>(Qb, WoT, bo, out, M, 2048, D);
}

// Round 9
// 327.840 us; speedup vs baseline: 3.0295x; 1.1828x over previous
//
#include <hip/hip_runtime.h>
#include <hip/hip_bf16.h>

typedef __attribute__((ext_vector_type(4)))  float f32x4;
typedef __attribute__((ext_vector_type(16))) float f32x16;
typedef __attribute__((ext_vector_type(8)))  short s16x8;
typedef __attribute__((ext_vector_type(4)))  short s16x4;
typedef __attribute__((ext_vector_type(4)))  float fvec4;

__device__ __forceinline__ short f2bf(float f) {
    union { float f; unsigned u; } x; x.f = f;
    unsigned r = x.u + 0x7fffu + ((x.u >> 16) & 1u);
    return (short)(r >> 16);
}

__device__ __forceinline__ short cvtbf(float f) {
    __hip_bfloat16 t = __float2bfloat16(f);   // compiler can pair-fuse to v_cvt_pk_bf16_f32
    return *reinterpret_cast<short*>(&t);
}

__device__ __forceinline__ void gload_lds16(const short* g, short* lds) {
    __builtin_amdgcn_global_load_lds(
        (const __attribute__((address_space(1))) void*)g,
        (__attribute__((address_space(3))) void*)lds, 16, 0, 0);
}

// ---------------- fp32 -> bf16 elementwise convert ----------------
__global__ __launch_bounds__(256) void convert_bf16(const float* __restrict__ X,
                                                    short* __restrict__ Y) {
    size_t i = ((size_t)blockIdx.x * 256 + threadIdx.x) * 8;
    fvec4 a = *(const fvec4*)&X[i];
    fvec4 b = *(const fvec4*)&X[i + 4];
    s16x8 o;
    o[0] = f2bf(a[0]); o[1] = f2bf(a[1]); o[2] = f2bf(a[2]); o[3] = f2bf(a[3]);
    o[4] = f2bf(b[0]); o[5] = f2bf(b[1]); o[6] = f2bf(b[2]); o[7] = f2bf(b[3]);
    *(s16x8*)&Y[i] = o;
}

// ---------------- fp32 [K][N] -> bf16 [N][K] transpose+convert ----------------
__global__ __launch_bounds__(256) void tconv(const float* __restrict__ W,
                                             short* __restrict__ Wt,
                                             int K, int N) {
    __shared__ float tile[32][33];
    const int k0 = blockIdx.x * 32, n0 = blockIdx.y * 32;
    const int tx = threadIdx.x & 31, ty = threadIdx.x >> 5;
    #pragma unroll
    for (int i = 0; i < 4; ++i) {
        int k = ty + i * 8;
        tile[k][tx] = W[(size_t)(k0 + k) * N + n0 + tx];
    }
    __syncthreads();
    #pragma unroll
    for (int i = 0; i < 4; ++i) {
        int n = ty + i * 8;
        Wt[(size_t)(n0 + n) * K + k0 + tx] = f2bf(tile[tx][n]);
    }
}

// ---------------- GEMM 128x128 (m97) fused K|V projection ----------------
// N = 1024: cols 0..511 -> K (bf16 row-major, bias_k); cols 512..1023 -> Vt
// (kv-axis bits 2<->3 permuted transposed store, bias_v). 512 blocks = 2/CU.
__global__ __launch_bounds__(256) void gemm_kv(const short* __restrict__ A,
                                               const short* __restrict__ Bt,
                                               const float* __restrict__ bias_k,
                                               const float* __restrict__ bias_v,
                                               short* __restrict__ Kout,
                                               short* __restrict__ Vout,
                                               int M, int N, int K) {
    __shared__ __align__(16) short As[128 * 64];
    __shared__ __align__(16) short Bs[128 * 64];
    const int tid = threadIdx.x, lane = tid & 63, wid = tid >> 6;
    const int wr = wid >> 1, wc = wid & 1;
    const int lr = lane & 15, g = lane >> 4;
    const int m0 = blockIdx.y * 128, n0 = blockIdx.x * 128;
    const int r8 = lane >> 3, c8 = lane & 7;

    f32x4 acc[4][4] = {};

    const short* ga = A  + (size_t)(m0 + wid * 8 + r8) * K + c8 * 8;
    const short* gb = Bt + (size_t)(n0 + wid * 8 + r8) * K + c8 * 8;

    for (int k0 = 0; k0 < K; k0 += 64) {
        #pragma unroll
        for (int it = 0; it < 4; ++it) {
            gload_lds16(ga + (size_t)(it * 32) * K + k0, &As[(wid * 8 + it * 32) * 64]);
            gload_lds16(gb + (size_t)(it * 32) * K + k0, &Bs[(wid * 8 + it * 32) * 64]);
        }
        __syncthreads();
        #pragma unroll
        for (int kk = 0; kk < 2; ++kk) {
            s16x8 af[4], bfv[4];
            #pragma unroll
            for (int m = 0; m < 4; ++m)
                af[m] = *(const s16x8*)&As[(wr * 64 + m * 16 + lr) * 64 + kk * 32 + g * 8];
            #pragma unroll
            for (int n = 0; n < 4; ++n)
                bfv[n] = *(const s16x8*)&Bs[(wc * 64 + n * 16 + lr) * 64 + kk * 32 + g * 8];
            #pragma unroll
            for (int m = 0; m < 4; ++m)
                #pragma unroll
                for (int n = 0; n < 4; ++n)
                    acc[m][n] = __builtin_amdgcn_mfma_f32_16x16x32_bf16(af[m], bfv[n], acc[m][n], 0, 0, 0);
        }
        __syncthreads();
    }
    if (n0 < 512) {
        // ---- K epilogue: row-major [8192][512] ----
        #pragma unroll
        for (int m = 0; m < 4; ++m)
            #pragma unroll
            for (int j = 0; j < 4; ++j) {
                int row = m0 + wr * 64 + m * 16 + g * 4 + j;
                #pragma unroll
                for (int n = 0; n < 4; ++n) {
                    int col = n0 + wc * 64 + n * 16 + lr;
                    Kout[(size_t)row * 512 + col] = f2bf(acc[m][n][j] + bias_k[col]);
                }
            }
    } else {
        // ---- V epilogue: transposed Vt[(b*4+kvh)*128+d][sigma(s)] ----
        #pragma unroll
        for (int m = 0; m < 4; ++m)
            #pragma unroll
            for (int n = 0; n < 4; ++n) {
                int vcol = n0 - 512 + wc * 64 + n * 16 + lr;   // 0..511
                int kvh = vcol >> 7, d = vcol & 127;
                int row0 = m0 + wr * 64 + m * 16 + g * 4;
                int b = row0 >> 11, s0 = row0 & 2047;
                // sigma: swap kv bits 2<->3 so attention feeds P in native C/D order
                int s0p = (s0 & ~15) | (((s0 >> 2) & 1) << 3) | (((s0 >> 3) & 1) << 2);
                s16x4 o;
                #pragma unroll
                for (int j = 0; j < 4; ++j) o[j] = f2bf(acc[m][n][j] + bias_v[vcol]);
                *(s16x4*)&Vout[(((size_t)b * 4 + kvh) * 128 + d) * 2048 + s0p] = o;
            }
    }
}

// ---------------- GEMM 256x256 phase-pipelined (counted vmcnt) ----------------
// XCD-swizzled grid (1-D, 256 blocks): XCD x owns m-rows 4x..4x+3 across all n
// -> A panels L2-resident per XCD, ~2.6x less LLC->L2 traffic.
template<int MODE>
__global__ __launch_bounds__(512, 1) void gemm256(const short* __restrict__ A,
                                                  const short* __restrict__ Bt,
                                                  const float* __restrict__ bias,
                                                  void* __restrict__ Cv,
                                                  int M, int N, int K) {
    __shared__ __align__(16) short As[2][16384];   // [dbuf][256 rows][64 k] swizzled
    __shared__ __align__(16) short Bs[2][16384];
    const int tid = threadIdx.x, lane = tid & 63, w = tid >> 6;
    const int wr = w >> 2, wc = w & 3;
    const int lr = lane & 15, g = lane >> 4;
    const int bid = blockIdx.x;
    const int xcd = bid & 7, ii = bid >> 3;
    const int m0 = (xcd * 4 + (ii & 3)) * 256;     // XCD owns 4 contiguous m-tiles
    const int n0 = (ii >> 2) * 256;
    const int r0 = w * 8 + (lane >> 3);
    const int sw = ((lane & 7) ^ ((lane >> 3) & 7)) * 8;
    const int swr = lr & 7;

    const short* ga = A  + (size_t)(m0 + r0) * K + sw;
    const short* gb = Bt + (size_t)(n0 + r0) * K + sw;

    f32x4 acc[8][4] = {};
    const int NT = K >> 6;

#define STAGE256(d, t) do {                                                     \
    const int kk0_ = (t) << 6;                                                  \
    _Pragma("unroll")                                                           \
    for (int it_ = 0; it_ < 4; ++it_) {                                         \
        gload_lds16(ga + (size_t)(it_ * 64) * K + kk0_, &As[d][it_ * 4096 + w * 512]); \
        gload_lds16(gb + (size_t)(it_ * 64) * K + kk0_, &Bs[d][it_ * 4096 + w * 512]); \
    }                                                                           \
} while (0)

    STAGE256(0, 0);

    for (int T = 0; T < NT; ++T) {
        const int d = T & 1;
        if (T + 1 < NT) {
            STAGE256((T + 1) & 1, T + 1);
            asm volatile("s_waitcnt vmcnt(8)" ::: "memory");
        } else {
            asm volatile("s_waitcnt vmcnt(0)" ::: "memory");
        }
        __builtin_amdgcn_s_barrier();
        __builtin_amdgcn_sched_barrier(0);
        s16x8 bf[4][2];
        #pragma unroll
        for (int n = 0; n < 4; ++n)
            #pragma unroll
            for (int kk = 0; kk < 2; ++kk)
                bf[n][kk] = *(const s16x8*)&Bs[d][(wc * 64 + n * 16 + lr) * 64 +
                                                 (((kk << 2) | g) ^ swr) * 8];
        #pragma unroll
        for (int p = 0; p < 4; ++p) {
            s16x8 af[2][2];
            #pragma unroll
            for (int mm = 0; mm < 2; ++mm)
                #pragma unroll
                for (int kk = 0; kk < 2; ++kk)
                    af[mm][kk] = *(const s16x8*)&As[d][(wr * 128 + (p * 2 + mm) * 16 + lr) * 64 +
                                                      (((kk << 2) | g) ^ swr) * 8];
            __builtin_amdgcn_s_setprio(1);
            #pragma unroll
            for (int kk = 0; kk < 2; ++kk)
                #pragma unroll
                for (int mm = 0; mm < 2; ++mm)
                    #pragma unroll
                    for (int n = 0; n < 4; ++n)
                        acc[p * 2 + mm][n] = __builtin_amdgcn_mfma_f32_16x16x32_bf16(
                            af[mm][kk], bf[n][kk], acc[p * 2 + mm][n], 0, 0, 0);
            __builtin_amdgcn_s_setprio(0);
            __builtin_amdgcn_s_barrier();
        }
        __builtin_amdgcn_sched_barrier(0);
    }
    #pragma unroll
    for (int m = 0; m < 8; ++m)
        #pragma unroll
        for (int j = 0; j < 4; ++j) {
            int row = m0 + wr * 128 + m * 16 + g * 4 + j;
            #pragma unroll
            for (int n = 0; n < 4; ++n) {
                int col = n0 + wc * 64 + n * 16 + lr;
                float v = acc[m][n][j] + bias[col];
                if constexpr (MODE == 1) ((short*)Cv)[(size_t)row * N + col] = f2bf(v);
                else                     ((float*)Cv)[(size_t)row * N + col] = v;
            }
        }
#undef STAGE256
}

// ---------------- Flash attention: 8 waves x 32 q-rows, KVBLK=64, 32x32x16 ----
// In-register softmax; P feeds PV in native C/D order (V kv-axis pre-permuted).
// bid remap: all 32 blocks sharing one (b,kvh) K/V stream land on one XCD.
#define SC2 0.12751743f   // (1/sqrt(128)) * log2(e)

__global__ __launch_bounds__(512, 1) void attn_kernel(const short* __restrict__ Q,
                                                      const short* __restrict__ Kg,
                                                      const short* __restrict__ Vtg,
                                                      short* __restrict__ Oa) {
    __shared__ __align__(16) short Klds[2][8192];   // [64 kv][128 d], 16B-slot XOR-swizzled
    __shared__ __align__(16) short Vlds[2][8192];   // [128 d][64 kv(perm)], swizzled
    const int tid = threadIdx.x;
    const int lane = tid & 63, w = tid >> 6;
    const int l31 = lane & 31, hi = lane >> 5, e7 = lane & 7;
    const int ve = hi ^ e7;

    const int bid = blockIdx.x;
    // bid = j*16 + grp: grp = b*4+kvh -> XCD = grp%8 (2 kv-groups per XCD)
    const int grp = bid & 15, j = bid >> 4;
    const int b = grp >> 2, kvh = grp & 3;
    const int h = kvh * 4 + (j & 3);
    const int qtp = (j >> 2) & 3, ph = j >> 4;
    const int qt = ph ? (3 - qtp) : (4 + qtp);
    const int qb = qt << 8;

    const int q_min = qb + w * 32;
    const int qg = q_min + l31;
    const size_t qrow = (size_t)b * 2048 + qg;

    s16x8 qf[8];
    #pragma unroll
    for (int c = 0; c < 8; ++c)
        qf[c] = *(const s16x8*)&Q[qrow * 2048 + h * 128 + c * 16 + hi * 8];

    f32x16 oacc[4] = {};
    // m_run init must stay >> mask value (-1e30) so fully-masked rows give p=0.
    float m_run = -1e28f, l_run = 0.f;

    const int nt = (qb >> 6) + 4;

    const short* Kbase = Kg + ((size_t)b * 2048) * 512 + kvh * 128;
    const short* Vbase = Vtg + ((size_t)(b * 4 + kvh)) * 128 * 2048;

    const int krow0 = w * 4 + (lane >> 4), kslot = lane & 15;
    const int vrow0 = w * 8 + (lane >> 3), vslot = lane & 7;

#define STAGE(buf, t) do {                                                        \
    const int kv0_ = (t) << 6;                                                    \
    _Pragma("unroll")                                                             \
    for (int s_ = 0; s_ < 2; ++s_) {                                              \
        int kr = s_ * 32 + krow0;                                                 \
        gload_lds16(Kbase + (size_t)(kv0_ + kr) * 512 + (kslot ^ (kr & 7)) * 8,   \
                    &Klds[buf][s_ * 4096 + w * 512]);                             \
        int vr = s_ * 64 + vrow0;                                                 \
        gload_lds16(Vbase + (size_t)vr * 2048 + kv0_ + (vslot ^ (vr & 7)) * 8,    \
                    &Vlds[buf][s_ * 4096 + w * 512]);                             \
    }                                                                             \
} while (0)

    STAGE(0, 0);
    __syncthreads();

    int cur = 0;
    for (int t = 0; t < nt; ++t) {
        if (t + 1 < nt) STAGE(cur ^ 1, t + 1);
        #pragma unroll
        for (int st = 0; st < 2; ++st) {
            const int kvoff = (t << 6) + (st << 5);
            if (kvoff > q_min) break;       // wave-uniform: subtile beyond diagonal
            // ---- S^T = K Q^T for this 32-kv subtile ----
            f32x16 s = {};
            const short* kb = &Klds[cur][((st << 5) + l31) * 128];
            #pragma unroll
            for (int c = 0; c < 8; ++c) {
                s16x8 kf = *(const s16x8*)&kb[(((c << 1) ^ ve)) * 8];
                s = __builtin_amdgcn_mfma_f32_32x32x16_bf16(kf, qf[c], s, 0, 0, 0);
            }
            // ---- causal mask (only on the diagonal subtile) ----
            if (kvoff == q_min) {
                #pragma unroll
                for (int r = 0; r < 16; ++r) {
                    const int rw = (r & 3) + 8 * (r >> 2) + 4 * hi;
                    if (rw > l31) s[r] = -1e30f;
                }
            }
            // ---- in-register softmax (q = lane&31 across both halves) ----
            float m01 = fmaxf(s[0], s[1]),   m23 = fmaxf(s[2], s[3]);
            float m45 = fmaxf(s[4], s[5]),   m67 = fmaxf(s[6], s[7]);
            float m89 = fmaxf(s[8], s[9]),   mab = fmaxf(s[10], s[11]);
            float mcd = fmaxf(s[12], s[13]), mef = fmaxf(s[14], s[15]);
            float mA = fmaxf(fmaxf(m01, m23), fmaxf(m45, m67));
            float mB = fmaxf(fmaxf(m89, mab), fmaxf(mcd, mef));
            float pm = fmaxf(mA, mB);
            pm = fmaxf(pm, __shfl_xor(pm, 32));     // combine lane/partner halves
            if (!__all(pm <= m_run + 90.5f)) {      // defer-max, thr = 8 nats
                float mn = fmaxf(m_run, pm);
                float fs = __builtin_amdgcn_exp2f((m_run - mn) * SC2);
                l_run *= fs;
                #pragma unroll
                for (int dn = 0; dn < 4; ++dn)
                    #pragma unroll
                    for (int r = 0; r < 16; ++r) oacc[dn][r] *= fs;
                m_run = mn;
            }
            const float mb2 = m_run * SC2;
            #pragma unroll
            for (int r = 0; r < 16; ++r)
                s[r] = __builtin_amdgcn_exp2f(fmaf(s[r], SC2, -mb2));
            float s01 = s[0] + s[1],   s23 = s[2] + s[3];
            float s45 = s[4] + s[5],   s67 = s[6] + s[7];
            float s89 = s[8] + s[9],   sab = s[10] + s[11];
            float scd = s[12] + s[13], sef = s[14] + s[15];
            float sAB = ((s01 + s23) + (s45 + s67)) + ((s89 + sab) + (scd + sef));
            l_run += sAB + __shfl_xor(sAB, 32);     // own + partner halves
            // ---- P -> bf16 PV fragments: native order (V pre-permuted) ----
            s16x8 pa0, pa1;
            #pragma unroll
            for (int jj = 0; jj < 8; ++jj) { pa0[jj] = cvtbf(s[jj]); pa1[jj] = cvtbf(s[8 + jj]); }
            // ---- O^T += Vt P ----
            const short* vb = &Vlds[cur][l31 * 64];
            #pragma unroll
            for (int dn = 0; dn < 4; ++dn) {
                s16x8 vf = *(const s16x8*)&vb[dn * 2048 + (((st << 2) ^ ve)) * 8];
                oacc[dn] = __builtin_amdgcn_mfma_f32_32x32x16_bf16(vf, pa0, oacc[dn], 0, 0, 0);
            }
            #pragma unroll
            for (int dn = 0; dn < 4; ++dn) {
                s16x8 vf = *(const s16x8*)&vb[dn * 2048 + ((((st << 2) | 2) ^ ve)) * 8];
                oacc[dn] = __builtin_amdgcn_mfma_f32_32x32x16_bf16(vf, pa1, oacc[dn], 0, 0, 0);
            }
        }
        __syncthreads();
        cur ^= 1;
    }
    // ---- normalize + store: lane owns q = qg; d = dn*32 + u*8 + 4hi + j ----
    const float inv = 1.0f / l_run;
    const size_t obase = qrow * 2048 + h * 128;
    #pragma unroll
    for (int dn = 0; dn < 4; ++dn)
        #pragma unroll
        for (int u = 0; u < 4; ++u) {
            s16x4 o;
            #pragma unroll
            for (int jj = 0; jj < 4; ++jj) o[jj] = cvtbf(oacc[dn][u * 4 + jj] * inv);
            *(s16x4*)&Oa[obase + dn * 32 + u * 8 + hi * 4] = o;
        }
#undef STAGE
}

extern "C" void kernel_launch(void* const* d_in, const int* in_sizes, int n_in,
                              void* d_out, int out_size, void* d_ws, size_t ws_size,
                              hipStream_t stream) {
    const float* x  = (const float*)d_in[0];
    const float* Wq = (const float*)d_in[1];
    const float* bq = (const float*)d_in[2];
    const float* Wk = (const float*)d_in[3];
    const float* bk = (const float*)d_in[4];
    const float* Wv = (const float*)d_in[5];
    const float* bv = (const float*)d_in[6];
    const float* Wo = (const float*)d_in[7];
    const float* bo = (const float*)d_in[8];
    float* out = (float*)d_out;

    // ws (80 MiB): Xb [0,32M) -> WoT reuse; Qb [32M,64M) (attn in-place); Kb [64M,72M); Vt [72M,80M)
    char* ws = (char*)d_ws;
    short* Xb  = (short*)(ws);
    short* Qb  = (short*)(ws + (size_t)33554432);
    short* Kb  = (short*)(ws + (size_t)67108864);
    short* Vt  = (short*)(ws + (size_t)75497472);
    short* WoT = (short*)(ws);                      // after Xb dead
    char* dob = (char*)d_out;                       // d_out as scratch until final GEMM
    short* WqT  = (short*)(dob);
    short* WkvT = (short*)(dob + (size_t)8388608);  // WkT | WvT contiguous = [1024][2048]

    const int M = 8192, D = 2048;

    convert_bf16<<<dim3((M * D) / (256 * 8)), 256, 0, stream>>>(x, Xb);
    tconv<<<dim3(64, 64), 256, 0, stream>>>(Wq, WqT, D, D);
    tconv<<<dim3(64, 16), 256, 0, stream>>>(Wk, WkvT, D, 512);
    tconv<<<dim3(64, 16), 256, 0, stream>>>(Wv, WkvT + (size_t)512 * D, D, 512);

    gemm256<1><<<dim3(256), 512, 0, stream>>>(Xb, WqT, bq, Qb, M, 2048, D);
    gemm_kv<<<dim3(8, 64), 256, 0, stream>>>(Xb, WkvT, bk, bv, Kb, Vt, M, 1024, D);

    tconv<<<dim3(64, 64), 256, 0, stream>>>(Wo, WoT, D, D);

    attn_kernel<<<dim3(512), 512, 0, stream>>>(Qb, Kb, Vt, Qb);

    gemm256<0><<<dim3(256), 512, 0, stream>>>(Qb, WoT, bo, out, M, 2048, D);
}